// Round 6
// baseline (1461.229 us; speedup 1.0000x reference)
//
#include <hip/hip_runtime.h>

// SGNet on MI355X. fp32 in/out, internal bf16 MFMA pipeline, fp32 master GRU
// states. Round-6: suffix-softmax decoder attention (logits are td-invariant),
// dh2i fused into decoder GRU kernel (2 dispatches/step), reg-head fused into
// head GEMM epilogue via atomics (ghid eliminated).

typedef unsigned short u16;
typedef __attribute__((ext_vector_type(8))) short bf16x8;
typedef __attribute__((ext_vector_type(4))) float f32x4;

static __device__ __forceinline__ float b2f(u16 u) {
  union { float f; unsigned int i; } x; x.i = ((unsigned int)u) << 16; return x.f;
}
static __device__ __forceinline__ u16 f2b(float f) {
  unsigned int u = __float_as_uint(f);
  unsigned int r = (u + 0x7FFFu + ((u >> 16) & 1u)) >> 16;
  return (u16)r;
}
static __device__ __forceinline__ float fsig(float x) {
  return __fdividef(1.f, 1.f + __expf(-x));
}
static __device__ __forceinline__ float ftanh(float x) {
  return 1.f - __fdividef(2.f, __expf(2.f * x) + 1.f);
}

// ---------------------------------------------------------------- all transposes, one dispatch
struct TransArgs {
  const float* in[13];
  u16* out[13];
  int K[13], N[13], t0[13], nx[13];
};

__global__ __launch_bounds__(256) void transpose_all(TransArgs ta) {
  int bid = blockIdx.x;
  int i = 0;
  for (int k = 1; k < 13; k++) if (bid >= ta.t0[k]) i = k;
  const float* in = ta.in[i];
  u16* out = ta.out[i];
  int K = ta.K[i], N = ta.N[i];
  int local = bid - ta.t0[i];
  int nx = ta.nx[i];
  int tx = local % nx, ty = local / nx;
  __shared__ u16 tbuf[32][33];
  int n0 = tx * 32, k0 = ty * 32;
  int x = threadIdx.x & 31, y = threadIdx.x >> 5;  // 32 x 8
  for (int q = 0; q < 4; q++) tbuf[y + 8 * q][x] = f2b(in[(size_t)(k0 + y + 8 * q) * N + n0 + x]);
  __syncthreads();
  for (int q = 0; q < 4; q++) out[(size_t)(n0 + y + 8 * q) * K + k0 + x] = tbuf[x][y + 8 * q];
}

// ---------------------------------------------------------------- embed (K=6)
__global__ __launch_bounds__(256) void embed_kernel(const float* __restrict__ inp,
                                                    const float* __restrict__ w,
                                                    const float* __restrict__ bias,
                                                    u16* __restrict__ traj) {
  int t = blockIdx.x * 256 + threadIdx.x;             // 8*512*512
  int h = t & 511, b = (t >> 9) & 511, e = t >> 18;
  float acc = bias[h];
  for (int i = 0; i < 6; i++) acc += inp[(b * 8 + e) * 6 + i] * w[i * 512 + h];
  traj[((e * 512) + b) * 512 + h] = f2b(fmaxf(acc, 0.f));
}

// ---------------------------------------------------------------- 128-tile MFMA GEMM
// Dual-descriptor (blockIdx.z). A column-split: K-cols >= asplit read from A2.
// Output column routing: cols >= route_n go to Cb2. Optional fused reg-head:
// when regout!=null and n0<route_n, block computes relu(acc+b)@regw partials
// and atomicAdds into regout (goal-output indexing), writing no C.
struct GDesc {
  const u16* A; int lda;
  const u16* A2; int lda2; int asplit;
  const u16* W; int ldw;
  const float* bias;
  u16* Cb; int ldc;
  float* Cf;
  u16* Cb2; int ldc2; int route_n;
  int K; int relu; int nblk; int mblk;
  const float* regw; const float* regb; float* regout;
};

__global__ __launch_bounds__(256) void gemm128(GDesc d0, GDesc d1) {
  GDesc d = (blockIdx.z == 0) ? d0 : d1;
  if ((int)blockIdx.x >= d.nblk || (int)blockIdx.y >= d.mblk) return;
  __shared__ u16 As[128][72];   // 144B row (16B-aligned); 2-way banks (free)
  __shared__ u16 Bs[128][72];
  int tid = threadIdx.x;
  int m0 = blockIdx.y * 128, n0 = blockIdx.x * 128;
  int lane = tid & 63, wave = tid >> 6;
  int wr = wave >> 1, wc = wave & 1;
  int mrow = lane & 15, kq = (lane >> 4) * 8;
  int srow = tid >> 3, scol = (tid & 7) * 8;
  f32x4 acc[4][4] = {};

  for (int k0 = 0; k0 < d.K; k0 += 64) {
    const u16* Asrc; int Alda, kk;
    if (k0 < d.asplit) { Asrc = d.A; Alda = d.lda; kk = k0; }
    else               { Asrc = d.A2; Alda = d.lda2; kk = k0 - d.asplit; }
    __syncthreads();
#pragma unroll
    for (int p = 0; p < 4; p++) {
      int r = srow + p * 32;
      *(uint4*)&As[r][scol] = *(const uint4*)&Asrc[(size_t)(m0 + r) * Alda + kk + scol];
      *(uint4*)&Bs[r][scol] = *(const uint4*)&d.W[(size_t)(n0 + r) * d.ldw + k0 + scol];
    }
    __syncthreads();
#pragma unroll
    for (int ks = 0; ks < 2; ks++) {
      bf16x8 af[4], bf[4];
#pragma unroll
      for (int i = 0; i < 4; i++) {
        af[i] = *(const bf16x8*)&As[wr * 64 + i * 16 + mrow][ks * 32 + kq];
        bf[i] = *(const bf16x8*)&Bs[wc * 64 + i * 16 + mrow][ks * 32 + kq];
      }
#pragma unroll
      for (int i = 0; i < 4; i++)
#pragma unroll
        for (int j = 0; j < 4; j++)
          acc[i][j] = __builtin_amdgcn_mfma_f32_16x16x32_bf16(af[i], bf[j], acc[i][j], 0, 0, 0);
    }
  }
  int col = lane & 15, rq = (lane >> 4) * 4;
  bool isreg = (d.regout != nullptr) && (n0 < d.route_n);
  if (isreg) {
    float pr0[4][4] = {}, pr1[4][4] = {};
#pragma unroll
    for (int j = 0; j < 4; j++) {
      int n = n0 + wc * 64 + j * 16 + col;
      float bv = d.bias ? d.bias[n] : 0.f;
      float rw0 = d.regw[n * 2], rw1 = d.regw[n * 2 + 1];
#pragma unroll
      for (int i = 0; i < 4; i++)
#pragma unroll
        for (int r = 0; r < 4; r++) {
          float v = fmaxf(acc[i][j][r] + bv, 0.f);
          pr0[i][r] += v * rw0;
          pr1[i][r] += v * rw1;
        }
    }
#pragma unroll
    for (int i = 0; i < 4; i++)
#pragma unroll
      for (int r = 0; r < 4; r++)
#pragma unroll
        for (int o = 1; o < 16; o <<= 1) {
          pr0[i][r] += __shfl_xor(pr0[i][r], o);
          pr1[i][r] += __shfl_xor(pr1[i][r], o);
        }
    if (col == 0) {
      bool addb = (blockIdx.x == 0 && wc == 0);
#pragma unroll
      for (int i = 0; i < 4; i++)
#pragma unroll
        for (int r = 0; r < 4; r++) {
          int m = m0 + wr * 64 + i * 16 + rq + r;   // (e*12+t)*512 + b
          int ee = m / 6144; int rem = m - ee * 6144;
          int t = rem >> 9; int b = rem & 511;
          float* o = d.regout + ((size_t)(b * 8 + ee) * 12 + t) * 2;
          atomicAdd(o, pr0[i][r] + (addb ? d.regb[0] : 0.f));
          atomicAdd(o + 1, pr1[i][r] + (addb ? d.regb[1] : 0.f));
        }
    }
    return;
  }
#pragma unroll
  for (int j = 0; j < 4; j++) {
    int n = n0 + wc * 64 + j * 16 + col;
    float bv = d.bias ? d.bias[n] : 0.f;
    bool r2 = (n >= d.route_n);
    u16* cb = r2 ? d.Cb2 : d.Cb;
    int ldc = r2 ? d.ldc2 : d.ldc;
    int nn = r2 ? n - d.route_n : n;
#pragma unroll
    for (int i = 0; i < 4; i++)
#pragma unroll
      for (int r = 0; r < 4; r++) {
        int m = m0 + wr * 64 + i * 16 + rq + r;
        float v = acc[i][j][r] + bv;
        if (d.relu) v = fmaxf(v, 0.f);
        cb[(size_t)m * ldc + nn] = f2b(v);
        if (d.Cf) d.Cf[(size_t)m * d.ldc + n] = v;
      }
  }
}

// ---------------------------------------------------------------- decoder GRU + reg head + dh2i fused
// 256 blocks x 1024 threads; block owns 16 rows. Phase A: pointwise GRU (wave
// per row) + reg head + stash dh in LDS. Phase B: ddi = relu(dh @ dh2i^T + b)
// via MFMA (16 waves x 2 n-tiles, K=512). Phase C: coalesced ddi store.
__global__ __launch_bounds__(1024) void gru_dh2i_reg(const u16* __restrict__ gi,
                                                     const u16* __restrict__ gh,
                                                     float* __restrict__ hf,
                                                     u16* __restrict__ hb,
                                                     const u16* __restrict__ w_t,   // [512,512]
                                                     const float* __restrict__ wb,  // [512]
                                                     u16* __restrict__ ddi,
                                                     const float* __restrict__ rw,
                                                     const float* __restrict__ rb,
                                                     float* __restrict__ out, int td) {
  __shared__ u16 dhs[16][520];   // stride 1040B -> 4-bank shift/row, 2-way (free)
  __shared__ u16 dds[16][520];
  int tid = threadIdx.x;
  int lane = tid & 63, wave = tid >> 6;
  int r0 = blockIdx.x * 16;
  // ---- phase A: pointwise GRU, wave per row
  {
    int r = r0 + wave;
    int j8 = lane * 8;
    size_t base = (size_t)r * 1536 + j8;
    uint4 ir4 = *(const uint4*)&gi[base];
    uint4 iz4 = *(const uint4*)&gi[base + 512];
    uint4 in4 = *(const uint4*)&gi[base + 1024];
    uint4 hr4 = *(const uint4*)&gh[base];
    uint4 hz4 = *(const uint4*)&gh[base + 512];
    uint4 hn4 = *(const uint4*)&gh[base + 1024];
    const u16* irp = (const u16*)&ir4; const u16* izp = (const u16*)&iz4;
    const u16* inp = (const u16*)&in4; const u16* hrp = (const u16*)&hr4;
    const u16* hzp = (const u16*)&hz4; const u16* hnp = (const u16*)&hn4;
    size_t hoff = (size_t)r * 512 + j8;
    float hv[8];
    *(float4*)&hv[0] = *(const float4*)&hf[hoff];
    *(float4*)&hv[4] = *(const float4*)&hf[hoff + 4];
    u16 hbv[8];
    float p0 = 0.f, p1 = 0.f;
    for (int j = 0; j < 8; j++) {
      float rr = fsig(b2f(irp[j]) + b2f(hrp[j]));
      float zz = fsig(b2f(izp[j]) + b2f(hzp[j]));
      float nn = ftanh(b2f(inp[j]) + rr * b2f(hnp[j]));
      float ho = (1.f - zz) * nn + zz * hv[j];
      hv[j] = ho; hbv[j] = f2b(ho);
      p0 += ho * rw[(j8 + j) * 2];
      p1 += ho * rw[(j8 + j) * 2 + 1];
    }
    *(float4*)&hf[hoff] = *(const float4*)&hv[0];
    *(float4*)&hf[hoff + 4] = *(const float4*)&hv[4];
    *(uint4*)&hb[hoff] = *(const uint4*)&hbv[0];
    *(uint4*)&dhs[wave][j8] = *(const uint4*)&hbv[0];
    for (int o = 32; o; o >>= 1) { p0 += __shfl_down(p0, o); p1 += __shfl_down(p1, o); }
    if (lane == 0) {
      int e = r >> 9, b = r & 511;
      size_t off = ((size_t)(b * 8 + e) * 12 + td) * 2;
      out[off] = p0 + rb[0];
      out[off + 1] = p1 + rb[1];
    }
  }
  __syncthreads();
  // ---- phase B: ddi = relu(dh @ dh2i^T + b), 16 waves x 2 tiles of N=512
  int mrow = lane & 15, kq = (lane >> 4) * 8, rq4 = (lane >> 4) * 4;
#pragma unroll
  for (int q = 0; q < 2; q++) {
    int n0 = (wave * 2 + q) * 16;
    f32x4 acc = {};
#pragma unroll
    for (int ks = 0; ks < 16; ks++) {
      bf16x8 a = *(const bf16x8*)&dhs[mrow][ks * 32 + kq];
      bf16x8 bfr = *(const bf16x8*)&w_t[(size_t)(n0 + mrow) * 512 + ks * 32 + kq];
      acc = __builtin_amdgcn_mfma_f32_16x16x32_bf16(a, bfr, acc, 0, 0, 0);
    }
    float bv = wb[n0 + mrow];
#pragma unroll
    for (int x = 0; x < 4; x++)
      dds[rq4 + x][n0 + mrow] = f2b(fmaxf(acc[x] + bv, 0.f));
  }
  __syncthreads();
  // ---- phase C: coalesced store
  int rr = tid >> 6, c8 = (tid & 63) * 8;
  *(uint4*)&ddi[(size_t)(r0 + rr) * 512 + c8] = *(const uint4*)&dds[rr][c8];
}

// ---------------------------------------------------------------- goal_mega
// Prologue: encoder GRU pointwise (16 rows) + e2g MFMA. Then 12-step goal GRU
// + g2e + encoder attention (into gfe_out). 16 waves/block, 16 rows/block.
__global__ __launch_bounds__(1024) void goal_mega(const u16* __restrict__ gi_g,     // [512,1536]
                                                  const u16* __restrict__ gh_g,     // [512,1536]
                                                  float* __restrict__ teh_f,        // [512,512] fp32 master
                                                  u16* __restrict__ teh_out,        // [512,512] bf16 hist slot
                                                  const u16* __restrict__ e2g_t,    // [128,512]
                                                  const float* __restrict__ e2g_b,  // [128]
                                                  const u16* __restrict__ wih_t,    // [384,128]
                                                  const u16* __restrict__ whh_t,    // [384,128]
                                                  const float* __restrict__ bih,    // [384]
                                                  const float* __restrict__ bhh,    // [384]
                                                  const u16* __restrict__ g2i_t,    // [128,128]
                                                  const float* __restrict__ g2i_b,  // [128]
                                                  const u16* __restrict__ g2e_t,    // [128,128]
                                                  const float* __restrict__ g2e_b,  // [128]
                                                  const float* __restrict__ eaw,    // [128]
                                                  const float* __restrict__ eab,    // [1]
                                                  u16* __restrict__ goals,          // [12,512,128] e-slice
                                                  u16* __restrict__ gfe_out) {      // [512,128]
  __shared__ float ghf[16][128];
  __shared__ u16   ghb[16][136];
  __shared__ u16   gib[16][136];
  __shared__ float gi3[16][388];
  __shared__ float gh3[16][388];
  __shared__ u16   gfe_l[12][16][128];
  __shared__ u16   tehb[16][520];
  int tid = threadIdx.x;
  int r0 = blockIdx.x * 16;
  int lane = tid & 63, wave = tid >> 6;       // 16 waves
  int mrow = lane & 15, kq = (lane >> 4) * 8;
  int rq4 = (lane >> 4) * 4;

  // persistent B-fragments: phase-1 tiles {w, w+16, w+32} of 48
  bf16x8 Bf[3][4];
  float  bias1[3];
  int    n0s[3];
  bool   isIv[3];
#pragma unroll
  for (int i = 0; i < 3; i++) {
    int tt = wave + 16 * i;
    bool iI = tt < 24;
    int n0 = (iI ? tt : tt - 24) * 16;
    isIv[i] = iI; n0s[i] = n0;
    const u16* Wt = iI ? wih_t : whh_t;
#pragma unroll
    for (int ks = 0; ks < 4; ks++)
      Bf[i][ks] = *(const bf16x8*)&Wt[(n0 + mrow) * 128 + ks * 32 + kq];
    bias1[i] = (iI ? bih : bhh)[n0 + mrow];
  }
  // phase-3 fragments: waves 0-7 -> g2i, waves 8-15 -> g2e
  bf16x8 Gf[4];
  float bias3;
  {
    const u16* W3 = (wave < 8) ? g2i_t : g2e_t;
    const float* B3 = (wave < 8) ? g2i_b : g2e_b;
    int n0 = (wave & 7) * 16;
#pragma unroll
    for (int ks = 0; ks < 4; ks++)
      Gf[ks] = *(const bf16x8*)&W3[(n0 + mrow) * 128 + ks * 32 + kq];
    bias3 = B3[n0 + mrow];
  }

  // zero gib
  {
    u16* gz = &gib[0][0];
    for (int idx = tid; idx < 16 * 136; idx += 1024) gz[idx] = 0;
  }

  // prologue GRU: wave per row (row = wave), 8 elems/lane
  {
    int r = wave;
    int j8 = lane * 8;
    int grow = r0 + r;
    size_t base = (size_t)grow * 1536 + j8;
    uint4 ir4 = *(const uint4*)&gi_g[base];
    uint4 iz4 = *(const uint4*)&gi_g[base + 512];
    uint4 in4 = *(const uint4*)&gi_g[base + 1024];
    uint4 hr4 = *(const uint4*)&gh_g[base];
    uint4 hz4 = *(const uint4*)&gh_g[base + 512];
    uint4 hn4 = *(const uint4*)&gh_g[base + 1024];
    const u16* irp = (const u16*)&ir4; const u16* izp = (const u16*)&iz4;
    const u16* inp = (const u16*)&in4; const u16* hrp = (const u16*)&hr4;
    const u16* hzp = (const u16*)&hz4; const u16* hnp = (const u16*)&hn4;
    size_t hoff = (size_t)grow * 512 + j8;
    float hv[8];
    *(float4*)&hv[0] = *(const float4*)&teh_f[hoff];
    *(float4*)&hv[4] = *(const float4*)&teh_f[hoff + 4];
    u16 hbv[8];
    for (int j = 0; j < 8; j++) {
      float rr = fsig(b2f(irp[j]) + b2f(hrp[j]));
      float zz = fsig(b2f(izp[j]) + b2f(hzp[j]));
      float nn = ftanh(b2f(inp[j]) + rr * b2f(hnp[j]));
      float ho = (1.f - zz) * nn + zz * hv[j];
      hv[j] = ho; hbv[j] = f2b(ho);
    }
    *(float4*)&teh_f[hoff] = *(const float4*)&hv[0];
    *(float4*)&teh_f[hoff + 4] = *(const float4*)&hv[4];
    *(uint4*)&teh_out[hoff] = *(const uint4*)&hbv[0];
    *(uint4*)&tehb[r][j8] = *(const uint4*)&hbv[0];
  }
  __syncthreads();

  // e2g: gh0[16][128] = relu(tehb @ e2g_t^T + b), waves 0-7
  if (wave < 8) {
    int n0 = wave * 16;
    f32x4 acc = {};
#pragma unroll
    for (int ks = 0; ks < 16; ks++) {
      bf16x8 a = *(const bf16x8*)&tehb[mrow][ks * 32 + kq];
      bf16x8 b = *(const bf16x8*)&e2g_t[(size_t)(n0 + mrow) * 512 + ks * 32 + kq];
      acc = __builtin_amdgcn_mfma_f32_16x16x32_bf16(a, b, acc, 0, 0, 0);
    }
    int n = n0 + mrow;
    float bv = e2g_b[n];
#pragma unroll
    for (int r = 0; r < 4; r++) {
      float v = fmaxf(acc[r] + bv, 0.f);
      int m = rq4 + r;
      ghf[m][n] = v;
      ghb[m][n] = f2b(v);
    }
  }
  __syncthreads();

  for (int t = 0; t < 12; t++) {
    // phase 1: gi3 = gi@wih+bih ; gh3 = gh@whh+bhh
    bf16x8 agi[4], agh[4];
#pragma unroll
    for (int ks = 0; ks < 4; ks++) {
      agi[ks] = *(const bf16x8*)&gib[mrow][ks * 32 + kq];
      agh[ks] = *(const bf16x8*)&ghb[mrow][ks * 32 + kq];
    }
#pragma unroll
    for (int i = 0; i < 3; i++) {
      f32x4 acc = {};
#pragma unroll
      for (int ks = 0; ks < 4; ks++)
        acc = __builtin_amdgcn_mfma_f32_16x16x32_bf16(isIv[i] ? agi[ks] : agh[ks],
                                                      Bf[i][ks], acc, 0, 0, 0);
      float* G = isIv[i] ? &gi3[0][0] : &gh3[0][0];
      int n = n0s[i] + mrow;
#pragma unroll
      for (int r = 0; r < 4; r++)
        G[(rq4 + r) * 388 + n] = acc[r] + bias1[i];
    }
    __syncthreads();
    // phase 2: pointwise GRU + emit goals[t]
    for (int idx = tid; idx < 2048; idx += 1024) {
      int m = idx >> 7, j = idx & 127;
      float rr = fsig(gi3[m][j] + gh3[m][j]);
      float zz = fsig(gi3[m][128 + j] + gh3[m][128 + j]);
      float nn = ftanh(gi3[m][256 + j] + rr * gh3[m][256 + j]);
      float h = ghf[m][j];
      float ho = (1.f - zz) * nn + zz * h;
      ghf[m][j] = ho;
      u16 hb = f2b(ho);
      ghb[m][j] = hb;
      goals[(t * 512 + r0 + m) * 128 + j] = hb;
    }
    __syncthreads();
    // phase 3: waves 0-7: gib = relu(gh@g2i+b); waves 8-15: gfe_l[t] = relu(gh@g2e+b)
    {
      f32x4 acc = {};
#pragma unroll
      for (int ks = 0; ks < 4; ks++) {
        bf16x8 a = *(const bf16x8*)&ghb[mrow][ks * 32 + kq];
        acc = __builtin_amdgcn_mfma_f32_16x16x32_bf16(a, Gf[ks], acc, 0, 0, 0);
      }
      int n = (wave & 7) * 16 + mrow;
      if (wave < 8) {
#pragma unroll
        for (int r = 0; r < 4; r++)
          gib[rq4 + r][n] = f2b(fmaxf(acc[r] + bias3, 0.f));
      } else {
#pragma unroll
        for (int r = 0; r < 4; r++)
          gfe_l[t][rq4 + r][n] = f2b(fmaxf(acc[r] + bias3, 0.f));
      }
    }
    __syncthreads();
  }

  // encoder attention (wave w -> row w), write gfe carry
  {
    int m = wave;
    float w0 = eaw[lane], w1 = eaw[lane + 64];
    float eb = eab[0];
    float v0[12], v1[12], lg[12];
#pragma unroll
    for (int t = 0; t < 12; t++) {
      float a = b2f(gfe_l[t][m][lane]);
      float c = b2f(gfe_l[t][m][lane + 64]);
      v0[t] = a; v1[t] = c;
      float p = ftanh(a) * w0 + ftanh(c) * w1;
      for (int o = 32; o; o >>= 1) p += __shfl_xor(p, o);
      lg[t] = fmaxf(p + eb, 0.f);
    }
    float mx = lg[0];
#pragma unroll
    for (int t = 1; t < 12; t++) mx = fmaxf(mx, lg[t]);
    float s = 0.f;
#pragma unroll
    for (int t = 0; t < 12; t++) { lg[t] = __expf(lg[t] - mx); s += lg[t]; }
    float inv = __fdividef(1.f, s);
    float c0 = 0.f, c1 = 0.f;
#pragma unroll
    for (int t = 0; t < 12; t++) { c0 += lg[t] * inv * v0[t]; c1 += lg[t] * inv * v1[t]; }
    gfe_out[(r0 + m) * 128 + lane] = f2b(c0);
    gfe_out[(r0 + m) * 128 + lane + 64] = f2b(c1);
  }
}

// ---------------------------------------------------------------- decoder ctx, suffix softmax
// wave per (e,b) row. Logits are td-invariant; masked s<td contribute
// logit=relu(da_b) (value 0). With common max m: ctx[td] = S[td]/(td*eb+E[td]),
// S/E suffix sums -> all 12 td in one 12-step loop.
__global__ __launch_bounds__(256) void attn_ctx_all(const u16* __restrict__ gfd,  // [8,12,512,128]
                                                    const float* __restrict__ daw,
                                                    const float* __restrict__ dab,
                                                    u16* __restrict__ xctx) {      // [12,4096,128]
  int row = (blockIdx.x * 256 + threadIdx.x) >> 6;   // e*512 + b
  int lane = threadIdx.x & 63;
  int e = row >> 9, b = row & 511;
  float w0 = daw[lane], w1 = daw[lane + 64];
  float bias = dab[0];
  float v0[12], v1[12], lg[12];
#pragma unroll
  for (int s = 0; s < 12; s++) {
    size_t o = ((size_t)(e * 12 + s) * 512 + b) * 128;
    float a = b2f(gfd[o + lane]);
    float c = b2f(gfd[o + 64 + lane]);
    v0[s] = a; v1[s] = c;
    float p = ftanh(a) * w0 + ftanh(c) * w1;
    for (int o2 = 32; o2; o2 >>= 1) p += __shfl_xor(p, o2);
    lg[s] = fmaxf(p + bias, 0.f);
  }
  float base = fmaxf(bias, 0.f);
  float m = base;
#pragma unroll
  for (int s = 0; s < 12; s++) m = fmaxf(m, lg[s]);
  float eb = __expf(base - m);
  float el[12];
#pragma unroll
  for (int s = 0; s < 12; s++) el[s] = __expf(lg[s] - m);
  float S0 = 0.f, S1 = 0.f, sufE = 0.f;
#pragma unroll
  for (int td = 11; td >= 0; td--) {
    sufE += el[td];
    S0 += el[td] * v0[td];
    S1 += el[td] * v1[td];
    float inv = __fdividef(1.f, (float)td * eb + sufE);
    size_t o = ((size_t)td * 4096 + row) * 128;
    xctx[o + lane] = f2b(S0 * inv);
    xctx[o + lane + 64] = f2b(S1 * inv);
  }
}

// ================================================================ host
extern "C" void kernel_launch(void* const* d_in, const int* in_sizes, int n_in,
                              void* d_out, int out_size, void* d_ws, size_t ws_size,
                              hipStream_t stream) {
  const float* inp      = (const float*)d_in[0];
  const float* embed_w  = (const float*)d_in[1];
  const float* embed_b  = (const float*)d_in[2];
  const float* reg_w    = (const float*)d_in[3];
  const float* reg_b    = (const float*)d_in[4];
  const float* ea_w     = (const float*)d_in[5];
  const float* ea_b     = (const float*)d_in[6];
  const float* da_w     = (const float*)d_in[7];
  const float* da_b     = (const float*)d_in[8];
  const float* e2g_w    = (const float*)d_in[9];
  const float* e2g_b    = (const float*)d_in[10];
  const float* e2d_w    = (const float*)d_in[11];
  const float* e2d_b    = (const float*)d_in[12];
  const float* gh2i_w   = (const float*)d_in[13];
  const float* gh2i_b   = (const float*)d_in[14];
  const float* dh2i_w   = (const float*)d_in[15];
  const float* dh2i_b   = (const float*)d_in[16];
  const float* gh2t_w   = (const float*)d_in[17];
  const float* gh2t_b   = (const float*)d_in[18];
  const float* g2e_w    = (const float*)d_in[19];
  const float* g2e_b    = (const float*)d_in[20];
  const float* g2d_w    = (const float*)d_in[21];
  const float* g2d_b    = (const float*)d_in[22];
  const float* enc_wih  = (const float*)d_in[23];
  const float* enc_whh  = (const float*)d_in[24];
  const float* enc_bih  = (const float*)d_in[25];
  const float* enc_bhh  = (const float*)d_in[26];
  const float* goal_wih = (const float*)d_in[27];
  const float* goal_whh = (const float*)d_in[28];
  const float* goal_bih = (const float*)d_in[29];
  const float* goal_bhh = (const float*)d_in[30];
  const float* dec_wih  = (const float*)d_in[31];
  const float* dec_whh  = (const float*)d_in[32];
  const float* dec_bih  = (const float*)d_in[33];
  const float* dec_bhh  = (const float*)d_in[34];

  char* ws = (char*)d_ws;
  size_t off = 0;
  auto alloc = [&](size_t bytes) -> char* {
    char* p = ws + off; off += (bytes + 255) & ~(size_t)255; return p;
  };
  const size_t TSZ = 512 * 512;
  // ---- zero region (contiguous): teh_f, teh_hist, gfe_buf
  float* teh_f    = (float*)alloc(TSZ * 4);
  u16*   teh_hist = (u16*)  alloc(9 * TSZ * 2);
  u16*   gfe_buf  = (u16*)  alloc(512 * 128 * 2);
  size_t zero_bytes = off;
  u16*   traj     = (u16*)  alloc((size_t)8 * TSZ * 2);
  u16*   goals_all= (u16*)  alloc((size_t)8 * 6144 * 128 * 2); // [8][12,512,128]
  u16*   gfd      = (u16*)  alloc((size_t)49152 * 128 * 2);    // [8,12,512,128]
  u16*   xctx     = (u16*)  alloc((size_t)12 * 4096 * 128 * 2);
  float* dh_f     = (float*)alloc((size_t)4096 * 512 * 4);
  u16*   dh_b     = (u16*)  alloc((size_t)4096 * 512 * 2);
  u16*   ddi      = (u16*)  alloc((size_t)4096 * 512 * 2);
  u16*   giD      = (u16*)  alloc((size_t)4096 * 1536 * 2);
  u16*   ghD      = (u16*)  alloc((size_t)4096 * 1536 * 2);
  u16*   giE = giD, *ghE = ghD;                                // enc aliases rows 0:512
  u16* enc_wih_t  = (u16*)alloc((size_t)1536 * 640 * 2);
  u16* enc_whh_t  = (u16*)alloc((size_t)1536 * 512 * 2);
  u16* dec_wih_t  = (u16*)alloc((size_t)1536 * 640 * 2);
  u16* dec_whh_t  = (u16*)alloc((size_t)1536 * 512 * 2);
  u16* e2g_t      = (u16*)alloc(128 * 512 * 2);
  u16* e2d_t      = (u16*)alloc(512 * 512 * 2);
  u16* dh2i_t     = (u16*)alloc(512 * 512 * 2);
  u16* head_t     = (u16*)alloc(640 * 128 * 2);   // rows 0-511: gh2t_t, 512-639: g2d_t
  u16* g2e_t      = (u16*)alloc(128 * 128 * 2);
  u16* goal_wih_t = (u16*)alloc(384 * 128 * 2);
  u16* goal_whh_t = (u16*)alloc(384 * 128 * 2);
  u16* gh2i_t     = (u16*)alloc(128 * 128 * 2);
  float* head_b   = (float*)alloc(640 * 4);
  if (off > ws_size) return;

  float* out_goal = (float*)d_out;
  float* out_dec  = out_goal + (size_t)512 * 8 * 12 * 2;

  hipMemsetAsync(teh_f, 0, zero_bytes, stream);
  hipMemsetAsync(out_goal, 0, (size_t)512 * 8 * 12 * 2 * 4, stream);  // atomic accum target

  // ---- all weight transposes in one dispatch
  TransArgs ta;
  int ntile = 0, ti = 0;
  auto push = [&](const float* in, u16* out, int K, int N) {
    ta.in[ti] = in; ta.out[ti] = out; ta.K[ti] = K; ta.N[ti] = N;
    ta.t0[ti] = ntile; ta.nx[ti] = N / 32;
    ntile += (K / 32) * (N / 32); ti++;
  };
  push(enc_wih, enc_wih_t, 640, 1536);
  push(enc_whh, enc_whh_t, 512, 1536);
  push(dec_wih, dec_wih_t, 640, 1536);
  push(dec_whh, dec_whh_t, 512, 1536);
  push(e2g_w, e2g_t, 512, 128);
  push(e2d_w, e2d_t, 512, 512);
  push(dh2i_w, dh2i_t, 512, 512);
  push(gh2t_w, head_t, 128, 512);
  push(g2d_w, head_t + 512 * 128, 128, 128);
  push(g2e_w, g2e_t, 128, 128);
  push(goal_wih, goal_wih_t, 128, 384);
  push(goal_whh, goal_whh_t, 128, 384);
  push(gh2i_w, gh2i_t, 128, 128);
  transpose_all<<<ntile, 256, 0, stream>>>(ta);
  hipMemcpyAsync(head_b, gh2t_b, 512 * 4, hipMemcpyDeviceToDevice, stream);
  hipMemcpyAsync(head_b + 512, g2d_b, 128 * 4, hipMemcpyDeviceToDevice, stream);

  embed_kernel<<<8192, 256, 0, stream>>>(inp, embed_w, embed_b, traj);

  const int FAR = 1 << 30;

  // ---------------- encoder chain (2 dispatches per step)
  for (int e = 0; e < 8; ++e) {
    GDesc dgi{traj + (size_t)e * TSZ, 512, gfe_buf, 128, 512,
              enc_wih_t, 640, enc_bih, giE, 1536, nullptr,
              nullptr, 0, FAR, 640, 0, 12, 4, nullptr, nullptr, nullptr};
    GDesc dgh{teh_hist + (size_t)e * TSZ, 512, nullptr, 0, FAR,
              enc_whh_t, 512, enc_bhh, ghE, 1536, nullptr,
              nullptr, 0, FAR, 512, 0, 12, 4, nullptr, nullptr, nullptr};
    gemm128<<<dim3(12, 4, 2), 256, 0, stream>>>(dgi, dgh);
    goal_mega<<<32, 1024, 0, stream>>>(giE, ghE, teh_f, teh_hist + (size_t)(e + 1) * TSZ,
                                       e2g_t, e2g_b,
                                       goal_wih_t, goal_whh_t, goal_bih, goal_bhh,
                                       gh2i_t, gh2i_b, g2e_t, g2e_b, ea_w, ea_b,
                                       goals_all + (size_t)e * 6144 * 128, gfe_buf);
  }

  // ---------------- deferred batched encoder sinks
  {
    // z=0: head GEMM (cols<512: fused reg head -> out_goal atomics; cols>=512 -> gfd)
    // z=1: e2d (dh init)
    GDesc dhead{goals_all, 128, nullptr, 0, FAR,
                head_t, 128, head_b, nullptr, 512, nullptr,
                gfd, 128, 512, 128, 1, 5, 384, reg_w, reg_b, out_goal};
    GDesc de2d{teh_hist + TSZ, 512, nullptr, 0, FAR,
               e2d_t, 512, e2d_b, dh_b, 512, dh_f,
               nullptr, 0, FAR, 512, 1, 4, 32, nullptr, nullptr, nullptr};
    gemm128<<<dim3(5, 384, 2), 256, 0, stream>>>(dhead, de2d);
    attn_ctx_all<<<1024, 256, 0, stream>>>(gfd, da_w, da_b, xctx);
    GDesc dd0{dh_b, 512, nullptr, 0, FAR,
              dh2i_t, 512, dh2i_b, ddi, 512, nullptr,
              nullptr, 0, FAR, 512, 1, 4, 32, nullptr, nullptr, nullptr};
    gemm128<<<dim3(4, 32, 1), 256, 0, stream>>>(dd0, dd0);
  }

  // ---------------- batched decoder (2 dispatches per step)
  for (int td = 0; td < 12; ++td) {
    GDesc dgi{xctx + (size_t)td * 4096 * 128, 128, ddi, 512, 128,
              dec_wih_t, 640, dec_bih, giD, 1536, nullptr,
              nullptr, 0, FAR, 640, 0, 12, 32, nullptr, nullptr, nullptr};
    GDesc dgh{dh_b, 512, nullptr, 0, FAR,
              dec_whh_t, 512, dec_bhh, ghD, 1536, nullptr,
              nullptr, 0, FAR, 512, 0, 12, 32, nullptr, nullptr, nullptr};
    gemm128<<<dim3(12, 32, 2), 256, 0, stream>>>(dgi, dgh);
    gru_dh2i_reg<<<256, 1024, 0, stream>>>(giD, ghD, dh_f, dh_b, dh2i_t, dh2i_b, ddi,
                                           reg_w, reg_b, out_dec, td);
  }
}

// Round 7
// 1315.358 us; speedup vs baseline: 1.1109x; 1.1109x over previous
//
#include <hip/hip_runtime.h>

// SGNet on MI355X. fp32 in/out, internal bf16 MFMA pipeline, fp32 master GRU
// states. Round-7: dedicated fused head_reg kernel (goals->gh2t->reg in one
// pass, no atomics/ghid); head GEMM shrunk to g2d-only dual'd with e2d;
// gemm128 epilogue back to the proven r5 form. Keeps r6's suffix-softmax
// attention and gru+dh2i fusion.

typedef unsigned short u16;
typedef __attribute__((ext_vector_type(8))) short bf16x8;
typedef __attribute__((ext_vector_type(4))) float f32x4;

static __device__ __forceinline__ float b2f(u16 u) {
  union { float f; unsigned int i; } x; x.i = ((unsigned int)u) << 16; return x.f;
}
static __device__ __forceinline__ u16 f2b(float f) {
  unsigned int u = __float_as_uint(f);
  unsigned int r = (u + 0x7FFFu + ((u >> 16) & 1u)) >> 16;
  return (u16)r;
}
static __device__ __forceinline__ float fsig(float x) {
  return __fdividef(1.f, 1.f + __expf(-x));
}
static __device__ __forceinline__ float ftanh(float x) {
  return 1.f - __fdividef(2.f, __expf(2.f * x) + 1.f);
}

// ---------------------------------------------------------------- all transposes, one dispatch
struct TransArgs {
  const float* in[13];
  u16* out[13];
  int K[13], N[13], t0[13], nx[13];
};

__global__ __launch_bounds__(256) void transpose_all(TransArgs ta) {
  int bid = blockIdx.x;
  int i = 0;
  for (int k = 1; k < 13; k++) if (bid >= ta.t0[k]) i = k;
  const float* in = ta.in[i];
  u16* out = ta.out[i];
  int K = ta.K[i], N = ta.N[i];
  int local = bid - ta.t0[i];
  int nx = ta.nx[i];
  int tx = local % nx, ty = local / nx;
  __shared__ u16 tbuf[32][33];
  int n0 = tx * 32, k0 = ty * 32;
  int x = threadIdx.x & 31, y = threadIdx.x >> 5;  // 32 x 8
  for (int q = 0; q < 4; q++) tbuf[y + 8 * q][x] = f2b(in[(size_t)(k0 + y + 8 * q) * N + n0 + x]);
  __syncthreads();
  for (int q = 0; q < 4; q++) out[(size_t)(n0 + y + 8 * q) * K + k0 + x] = tbuf[x][y + 8 * q];
}

// ---------------------------------------------------------------- embed (K=6)
__global__ __launch_bounds__(256) void embed_kernel(const float* __restrict__ inp,
                                                    const float* __restrict__ w,
                                                    const float* __restrict__ bias,
                                                    u16* __restrict__ traj) {
  int t = blockIdx.x * 256 + threadIdx.x;             // 8*512*512
  int h = t & 511, b = (t >> 9) & 511, e = t >> 18;
  float acc = bias[h];
  for (int i = 0; i < 6; i++) acc += inp[(b * 8 + e) * 6 + i] * w[i * 512 + h];
  traj[((e * 512) + b) * 512 + h] = f2b(fmaxf(acc, 0.f));
}

// ---------------------------------------------------------------- 128-tile MFMA GEMM
// Dual-descriptor (blockIdx.z). A column-split: K-cols >= asplit read from A2.
// Output column routing: cols >= route_n go to Cb2.
struct GDesc {
  const u16* A; int lda;
  const u16* A2; int lda2; int asplit;
  const u16* W; int ldw;
  const float* bias;
  u16* Cb; int ldc;
  float* Cf;
  u16* Cb2; int ldc2; int route_n;
  int K; int relu; int nblk; int mblk;
};

__global__ __launch_bounds__(256) void gemm128(GDesc d0, GDesc d1) {
  GDesc d = (blockIdx.z == 0) ? d0 : d1;
  if ((int)blockIdx.x >= d.nblk || (int)blockIdx.y >= d.mblk) return;
  __shared__ u16 As[128][72];   // 144B row (16B-aligned); 2-way banks (free)
  __shared__ u16 Bs[128][72];
  int tid = threadIdx.x;
  int m0 = blockIdx.y * 128, n0 = blockIdx.x * 128;
  int lane = tid & 63, wave = tid >> 6;
  int wr = wave >> 1, wc = wave & 1;
  int mrow = lane & 15, kq = (lane >> 4) * 8;
  int srow = tid >> 3, scol = (tid & 7) * 8;
  f32x4 acc[4][4] = {};

  for (int k0 = 0; k0 < d.K; k0 += 64) {
    const u16* Asrc; int Alda, kk;
    if (k0 < d.asplit) { Asrc = d.A; Alda = d.lda; kk = k0; }
    else               { Asrc = d.A2; Alda = d.lda2; kk = k0 - d.asplit; }
    __syncthreads();
#pragma unroll
    for (int p = 0; p < 4; p++) {
      int r = srow + p * 32;
      *(uint4*)&As[r][scol] = *(const uint4*)&Asrc[(size_t)(m0 + r) * Alda + kk + scol];
      *(uint4*)&Bs[r][scol] = *(const uint4*)&d.W[(size_t)(n0 + r) * d.ldw + k0 + scol];
    }
    __syncthreads();
#pragma unroll
    for (int ks = 0; ks < 2; ks++) {
      bf16x8 af[4], bf[4];
#pragma unroll
      for (int i = 0; i < 4; i++) {
        af[i] = *(const bf16x8*)&As[wr * 64 + i * 16 + mrow][ks * 32 + kq];
        bf[i] = *(const bf16x8*)&Bs[wc * 64 + i * 16 + mrow][ks * 32 + kq];
      }
#pragma unroll
      for (int i = 0; i < 4; i++)
#pragma unroll
        for (int j = 0; j < 4; j++)
          acc[i][j] = __builtin_amdgcn_mfma_f32_16x16x32_bf16(af[i], bf[j], acc[i][j], 0, 0, 0);
    }
  }
  int col = lane & 15, rq = (lane >> 4) * 4;
#pragma unroll
  for (int j = 0; j < 4; j++) {
    int n = n0 + wc * 64 + j * 16 + col;
    float bv = d.bias ? d.bias[n] : 0.f;
    bool r2 = (n >= d.route_n);
    u16* cb = r2 ? d.Cb2 : d.Cb;
    int ldc = r2 ? d.ldc2 : d.ldc;
    int nn = r2 ? n - d.route_n : n;
#pragma unroll
    for (int i = 0; i < 4; i++)
#pragma unroll
      for (int r = 0; r < 4; r++) {
        int m = m0 + wr * 64 + i * 16 + rq + r;
        float v = acc[i][j][r] + bv;
        if (d.relu) v = fmaxf(v, 0.f);
        cb[(size_t)m * ldc + nn] = f2b(v);
        if (d.Cf) d.Cf[(size_t)m * d.ldc + n] = v;
      }
  }
}

// ---------------------------------------------------------------- fused goal head
// out[b,e,t] = relu(goals[m] @ gh2t^T + gh2t_b) @ reg_w + reg_b, m=(e*12+t)*512+b.
// Wave owns 16 rows; A-frags in registers; sweeps 32 n-tiles, contracting each
// relu'd tile with reg_w immediately (one live acc). No intermediate buffer.
__global__ __launch_bounds__(256) void head_reg(const u16* __restrict__ goals,   // [49152,128]
                                                const u16* __restrict__ w_t,     // [512,128] gh2t_t
                                                const float* __restrict__ wb,    // [512]
                                                const float* __restrict__ rw,    // [512,2]
                                                const float* __restrict__ rb,    // [2]
                                                float* __restrict__ out) {
  int tid = threadIdx.x;
  int lane = tid & 63, wave = tid >> 6;
  int rbase = blockIdx.x * 64 + wave * 16;
  int mrow = lane & 15, kq = (lane >> 4) * 8;
  int col = lane & 15, rq4 = (lane >> 4) * 4;
  bf16x8 a[4];
#pragma unroll
  for (int ks = 0; ks < 4; ks++)
    a[ks] = *(const bf16x8*)&goals[(size_t)(rbase + mrow) * 128 + ks * 32 + kq];
  float pr0[4] = {}, pr1[4] = {};
  for (int j = 0; j < 32; j++) {
    f32x4 acc = {};
#pragma unroll
    for (int ks = 0; ks < 4; ks++) {
      bf16x8 b = *(const bf16x8*)&w_t[(size_t)(j * 16 + mrow) * 128 + ks * 32 + kq];
      acc = __builtin_amdgcn_mfma_f32_16x16x32_bf16(a[ks], b, acc, 0, 0, 0);
    }
    int n = j * 16 + col;
    float bv = wb[n];
    float rw0 = rw[n * 2], rw1 = rw[n * 2 + 1];
#pragma unroll
    for (int r = 0; r < 4; r++) {
      float v = fmaxf(acc[r] + bv, 0.f);
      pr0[r] += v * rw0;
      pr1[r] += v * rw1;
    }
  }
#pragma unroll
  for (int r = 0; r < 4; r++)
#pragma unroll
    for (int o = 1; o < 16; o <<= 1) {
      pr0[r] += __shfl_xor(pr0[r], o);
      pr1[r] += __shfl_xor(pr1[r], o);
    }
  if (col == 0) {
#pragma unroll
    for (int r = 0; r < 4; r++) {
      int m = rbase + rq4 + r;                // (e*12+t)*512 + b
      int e = m / 6144; int rem = m - e * 6144;
      int t = rem >> 9; int b = rem & 511;
      float* o = out + ((size_t)(b * 8 + e) * 12 + t) * 2;
      o[0] = pr0[r] + rb[0];
      o[1] = pr1[r] + rb[1];
    }
  }
}

// ---------------------------------------------------------------- decoder GRU + reg head + dh2i fused
__global__ __launch_bounds__(1024) void gru_dh2i_reg(const u16* __restrict__ gi,
                                                     const u16* __restrict__ gh,
                                                     float* __restrict__ hf,
                                                     u16* __restrict__ hb,
                                                     const u16* __restrict__ w_t,   // [512,512]
                                                     const float* __restrict__ wb,  // [512]
                                                     u16* __restrict__ ddi,
                                                     const float* __restrict__ rw,
                                                     const float* __restrict__ rb,
                                                     float* __restrict__ out, int td) {
  __shared__ u16 dhs[16][520];   // stride 1040B -> 4-bank shift/row, 2-way (free)
  __shared__ u16 dds[16][520];
  int tid = threadIdx.x;
  int lane = tid & 63, wave = tid >> 6;
  int r0 = blockIdx.x * 16;
  // ---- phase A: pointwise GRU, wave per row
  {
    int r = r0 + wave;
    int j8 = lane * 8;
    size_t base = (size_t)r * 1536 + j8;
    uint4 ir4 = *(const uint4*)&gi[base];
    uint4 iz4 = *(const uint4*)&gi[base + 512];
    uint4 in4 = *(const uint4*)&gi[base + 1024];
    uint4 hr4 = *(const uint4*)&gh[base];
    uint4 hz4 = *(const uint4*)&gh[base + 512];
    uint4 hn4 = *(const uint4*)&gh[base + 1024];
    const u16* irp = (const u16*)&ir4; const u16* izp = (const u16*)&iz4;
    const u16* inp = (const u16*)&in4; const u16* hrp = (const u16*)&hr4;
    const u16* hzp = (const u16*)&hz4; const u16* hnp = (const u16*)&hn4;
    size_t hoff = (size_t)r * 512 + j8;
    float hv[8];
    *(float4*)&hv[0] = *(const float4*)&hf[hoff];
    *(float4*)&hv[4] = *(const float4*)&hf[hoff + 4];
    u16 hbv[8];
    float p0 = 0.f, p1 = 0.f;
    for (int j = 0; j < 8; j++) {
      float rr = fsig(b2f(irp[j]) + b2f(hrp[j]));
      float zz = fsig(b2f(izp[j]) + b2f(hzp[j]));
      float nn = ftanh(b2f(inp[j]) + rr * b2f(hnp[j]));
      float ho = (1.f - zz) * nn + zz * hv[j];
      hv[j] = ho; hbv[j] = f2b(ho);
      p0 += ho * rw[(j8 + j) * 2];
      p1 += ho * rw[(j8 + j) * 2 + 1];
    }
    *(float4*)&hf[hoff] = *(const float4*)&hv[0];
    *(float4*)&hf[hoff + 4] = *(const float4*)&hv[4];
    *(uint4*)&hb[hoff] = *(const uint4*)&hbv[0];
    *(uint4*)&dhs[wave][j8] = *(const uint4*)&hbv[0];
    for (int o = 32; o; o >>= 1) { p0 += __shfl_down(p0, o); p1 += __shfl_down(p1, o); }
    if (lane == 0) {
      int e = r >> 9, b = r & 511;
      size_t off = ((size_t)(b * 8 + e) * 12 + td) * 2;
      out[off] = p0 + rb[0];
      out[off + 1] = p1 + rb[1];
    }
  }
  __syncthreads();
  // ---- phase B: ddi = relu(dh @ dh2i^T + b), 16 waves x 2 tiles of N=512
  int mrow = lane & 15, kq = (lane >> 4) * 8, rq4 = (lane >> 4) * 4;
#pragma unroll
  for (int q = 0; q < 2; q++) {
    int n0 = (wave * 2 + q) * 16;
    f32x4 acc = {};
#pragma unroll
    for (int ks = 0; ks < 16; ks++) {
      bf16x8 a = *(const bf16x8*)&dhs[mrow][ks * 32 + kq];
      bf16x8 bfr = *(const bf16x8*)&w_t[(size_t)(n0 + mrow) * 512 + ks * 32 + kq];
      acc = __builtin_amdgcn_mfma_f32_16x16x32_bf16(a, bfr, acc, 0, 0, 0);
    }
    float bv = wb[n0 + mrow];
#pragma unroll
    for (int x = 0; x < 4; x++)
      dds[rq4 + x][n0 + mrow] = f2b(fmaxf(acc[x] + bv, 0.f));
  }
  __syncthreads();
  // ---- phase C: coalesced store
  int rr = tid >> 6, c8 = (tid & 63) * 8;
  *(uint4*)&ddi[(size_t)(r0 + rr) * 512 + c8] = *(const uint4*)&dds[rr][c8];
}

// ---------------------------------------------------------------- goal_mega
__global__ __launch_bounds__(1024) void goal_mega(const u16* __restrict__ gi_g,     // [512,1536]
                                                  const u16* __restrict__ gh_g,     // [512,1536]
                                                  float* __restrict__ teh_f,        // [512,512] fp32 master
                                                  u16* __restrict__ teh_out,        // [512,512] bf16 hist slot
                                                  const u16* __restrict__ e2g_t,    // [128,512]
                                                  const float* __restrict__ e2g_b,  // [128]
                                                  const u16* __restrict__ wih_t,    // [384,128]
                                                  const u16* __restrict__ whh_t,    // [384,128]
                                                  const float* __restrict__ bih,    // [384]
                                                  const float* __restrict__ bhh,    // [384]
                                                  const u16* __restrict__ g2i_t,    // [128,128]
                                                  const float* __restrict__ g2i_b,  // [128]
                                                  const u16* __restrict__ g2e_t,    // [128,128]
                                                  const float* __restrict__ g2e_b,  // [128]
                                                  const float* __restrict__ eaw,    // [128]
                                                  const float* __restrict__ eab,    // [1]
                                                  u16* __restrict__ goals,          // [12,512,128] e-slice
                                                  u16* __restrict__ gfe_out) {      // [512,128]
  __shared__ float ghf[16][128];
  __shared__ u16   ghb[16][136];
  __shared__ u16   gib[16][136];
  __shared__ float gi3[16][388];
  __shared__ float gh3[16][388];
  __shared__ u16   gfe_l[12][16][128];
  __shared__ u16   tehb[16][520];
  int tid = threadIdx.x;
  int r0 = blockIdx.x * 16;
  int lane = tid & 63, wave = tid >> 6;       // 16 waves
  int mrow = lane & 15, kq = (lane >> 4) * 8;
  int rq4 = (lane >> 4) * 4;

  // persistent B-fragments: phase-1 tiles {w, w+16, w+32} of 48
  bf16x8 Bf[3][4];
  float  bias1[3];
  int    n0s[3];
  bool   isIv[3];
#pragma unroll
  for (int i = 0; i < 3; i++) {
    int tt = wave + 16 * i;
    bool iI = tt < 24;
    int n0 = (iI ? tt : tt - 24) * 16;
    isIv[i] = iI; n0s[i] = n0;
    const u16* Wt = iI ? wih_t : whh_t;
#pragma unroll
    for (int ks = 0; ks < 4; ks++)
      Bf[i][ks] = *(const bf16x8*)&Wt[(n0 + mrow) * 128 + ks * 32 + kq];
    bias1[i] = (iI ? bih : bhh)[n0 + mrow];
  }
  // phase-3 fragments: waves 0-7 -> g2i, waves 8-15 -> g2e
  bf16x8 Gf[4];
  float bias3;
  {
    const u16* W3 = (wave < 8) ? g2i_t : g2e_t;
    const float* B3 = (wave < 8) ? g2i_b : g2e_b;
    int n0 = (wave & 7) * 16;
#pragma unroll
    for (int ks = 0; ks < 4; ks++)
      Gf[ks] = *(const bf16x8*)&W3[(n0 + mrow) * 128 + ks * 32 + kq];
    bias3 = B3[n0 + mrow];
  }

  // zero gib
  {
    u16* gz = &gib[0][0];
    for (int idx = tid; idx < 16 * 136; idx += 1024) gz[idx] = 0;
  }

  // prologue GRU: wave per row (row = wave), 8 elems/lane
  {
    int r = wave;
    int j8 = lane * 8;
    int grow = r0 + r;
    size_t base = (size_t)grow * 1536 + j8;
    uint4 ir4 = *(const uint4*)&gi_g[base];
    uint4 iz4 = *(const uint4*)&gi_g[base + 512];
    uint4 in4 = *(const uint4*)&gi_g[base + 1024];
    uint4 hr4 = *(const uint4*)&gh_g[base];
    uint4 hz4 = *(const uint4*)&gh_g[base + 512];
    uint4 hn4 = *(const uint4*)&gh_g[base + 1024];
    const u16* irp = (const u16*)&ir4; const u16* izp = (const u16*)&iz4;
    const u16* inp = (const u16*)&in4; const u16* hrp = (const u16*)&hr4;
    const u16* hzp = (const u16*)&hz4; const u16* hnp = (const u16*)&hn4;
    size_t hoff = (size_t)grow * 512 + j8;
    float hv[8];
    *(float4*)&hv[0] = *(const float4*)&teh_f[hoff];
    *(float4*)&hv[4] = *(const float4*)&teh_f[hoff + 4];
    u16 hbv[8];
    for (int j = 0; j < 8; j++) {
      float rr = fsig(b2f(irp[j]) + b2f(hrp[j]));
      float zz = fsig(b2f(izp[j]) + b2f(hzp[j]));
      float nn = ftanh(b2f(inp[j]) + rr * b2f(hnp[j]));
      float ho = (1.f - zz) * nn + zz * hv[j];
      hv[j] = ho; hbv[j] = f2b(ho);
    }
    *(float4*)&teh_f[hoff] = *(const float4*)&hv[0];
    *(float4*)&teh_f[hoff + 4] = *(const float4*)&hv[4];
    *(uint4*)&teh_out[hoff] = *(const uint4*)&hbv[0];
    *(uint4*)&tehb[r][j8] = *(const uint4*)&hbv[0];
  }
  __syncthreads();

  // e2g: gh0[16][128] = relu(tehb @ e2g_t^T + b), waves 0-7
  if (wave < 8) {
    int n0 = wave * 16;
    f32x4 acc = {};
#pragma unroll
    for (int ks = 0; ks < 16; ks++) {
      bf16x8 a = *(const bf16x8*)&tehb[mrow][ks * 32 + kq];
      bf16x8 b = *(const bf16x8*)&e2g_t[(size_t)(n0 + mrow) * 512 + ks * 32 + kq];
      acc = __builtin_amdgcn_mfma_f32_16x16x32_bf16(a, b, acc, 0, 0, 0);
    }
    int n = n0 + mrow;
    float bv = e2g_b[n];
#pragma unroll
    for (int r = 0; r < 4; r++) {
      float v = fmaxf(acc[r] + bv, 0.f);
      int m = rq4 + r;
      ghf[m][n] = v;
      ghb[m][n] = f2b(v);
    }
  }
  __syncthreads();

  for (int t = 0; t < 12; t++) {
    // phase 1: gi3 = gi@wih+bih ; gh3 = gh@whh+bhh
    bf16x8 agi[4], agh[4];
#pragma unroll
    for (int ks = 0; ks < 4; ks++) {
      agi[ks] = *(const bf16x8*)&gib[mrow][ks * 32 + kq];
      agh[ks] = *(const bf16x8*)&ghb[mrow][ks * 32 + kq];
    }
#pragma unroll
    for (int i = 0; i < 3; i++) {
      f32x4 acc = {};
#pragma unroll
      for (int ks = 0; ks < 4; ks++)
        acc = __builtin_amdgcn_mfma_f32_16x16x32_bf16(isIv[i] ? agi[ks] : agh[ks],
                                                      Bf[i][ks], acc, 0, 0, 0);
      float* G = isIv[i] ? &gi3[0][0] : &gh3[0][0];
      int n = n0s[i] + mrow;
#pragma unroll
      for (int r = 0; r < 4; r++)
        G[(rq4 + r) * 388 + n] = acc[r] + bias1[i];
    }
    __syncthreads();
    // phase 2: pointwise GRU + emit goals[t]
    for (int idx = tid; idx < 2048; idx += 1024) {
      int m = idx >> 7, j = idx & 127;
      float rr = fsig(gi3[m][j] + gh3[m][j]);
      float zz = fsig(gi3[m][128 + j] + gh3[m][128 + j]);
      float nn = ftanh(gi3[m][256 + j] + rr * gh3[m][256 + j]);
      float h = ghf[m][j];
      float ho = (1.f - zz) * nn + zz * h;
      ghf[m][j] = ho;
      u16 hb = f2b(ho);
      ghb[m][j] = hb;
      goals[(t * 512 + r0 + m) * 128 + j] = hb;
    }
    __syncthreads();
    // phase 3: waves 0-7: gib = relu(gh@g2i+b); waves 8-15: gfe_l[t] = relu(gh@g2e+b)
    {
      f32x4 acc = {};
#pragma unroll
      for (int ks = 0; ks < 4; ks++) {
        bf16x8 a = *(const bf16x8*)&ghb[mrow][ks * 32 + kq];
        acc = __builtin_amdgcn_mfma_f32_16x16x32_bf16(a, Gf[ks], acc, 0, 0, 0);
      }
      int n = (wave & 7) * 16 + mrow;
      if (wave < 8) {
#pragma unroll
        for (int r = 0; r < 4; r++)
          gib[rq4 + r][n] = f2b(fmaxf(acc[r] + bias3, 0.f));
      } else {
#pragma unroll
        for (int r = 0; r < 4; r++)
          gfe_l[t][rq4 + r][n] = f2b(fmaxf(acc[r] + bias3, 0.f));
      }
    }
    __syncthreads();
  }

  // encoder attention (wave w -> row w), write gfe carry
  {
    int m = wave;
    float w0 = eaw[lane], w1 = eaw[lane + 64];
    float eb = eab[0];
    float v0[12], v1[12], lg[12];
#pragma unroll
    for (int t = 0; t < 12; t++) {
      float a = b2f(gfe_l[t][m][lane]);
      float c = b2f(gfe_l[t][m][lane + 64]);
      v0[t] = a; v1[t] = c;
      float p = ftanh(a) * w0 + ftanh(c) * w1;
      for (int o = 32; o; o >>= 1) p += __shfl_xor(p, o);
      lg[t] = fmaxf(p + eb, 0.f);
    }
    float mx = lg[0];
#pragma unroll
    for (int t = 1; t < 12; t++) mx = fmaxf(mx, lg[t]);
    float s = 0.f;
#pragma unroll
    for (int t = 0; t < 12; t++) { lg[t] = __expf(lg[t] - mx); s += lg[t]; }
    float inv = __fdividef(1.f, s);
    float c0 = 0.f, c1 = 0.f;
#pragma unroll
    for (int t = 0; t < 12; t++) { c0 += lg[t] * inv * v0[t]; c1 += lg[t] * inv * v1[t]; }
    gfe_out[(r0 + m) * 128 + lane] = f2b(c0);
    gfe_out[(r0 + m) * 128 + lane + 64] = f2b(c1);
  }
}

// ---------------------------------------------------------------- decoder ctx, suffix softmax
__global__ __launch_bounds__(256) void attn_ctx_all(const u16* __restrict__ gfd,  // [8,12,512,128]
                                                    const float* __restrict__ daw,
                                                    const float* __restrict__ dab,
                                                    u16* __restrict__ xctx) {      // [12,4096,128]
  int row = (blockIdx.x * 256 + threadIdx.x) >> 6;   // e*512 + b
  int lane = threadIdx.x & 63;
  int e = row >> 9, b = row & 511;
  float w0 = daw[lane], w1 = daw[lane + 64];
  float bias = dab[0];
  float v0[12], v1[12], lg[12];
#pragma unroll
  for (int s = 0; s < 12; s++) {
    size_t o = ((size_t)(e * 12 + s) * 512 + b) * 128;
    float a = b2f(gfd[o + lane]);
    float c = b2f(gfd[o + 64 + lane]);
    v0[s] = a; v1[s] = c;
    float p = ftanh(a) * w0 + ftanh(c) * w1;
    for (int o2 = 32; o2; o2 >>= 1) p += __shfl_xor(p, o2);
    lg[s] = fmaxf(p + bias, 0.f);
  }
  float base = fmaxf(bias, 0.f);
  float m = base;
#pragma unroll
  for (int s = 0; s < 12; s++) m = fmaxf(m, lg[s]);
  float eb = __expf(base - m);
  float el[12];
#pragma unroll
  for (int s = 0; s < 12; s++) el[s] = __expf(lg[s] - m);
  float S0 = 0.f, S1 = 0.f, sufE = 0.f;
#pragma unroll
  for (int td = 11; td >= 0; td--) {
    sufE += el[td];
    S0 += el[td] * v0[td];
    S1 += el[td] * v1[td];
    float inv = __fdividef(1.f, (float)td * eb + sufE);
    size_t o = ((size_t)td * 4096 + row) * 128;
    xctx[o + lane] = f2b(S0 * inv);
    xctx[o + lane + 64] = f2b(S1 * inv);
  }
}

// ================================================================ host
extern "C" void kernel_launch(void* const* d_in, const int* in_sizes, int n_in,
                              void* d_out, int out_size, void* d_ws, size_t ws_size,
                              hipStream_t stream) {
  const float* inp      = (const float*)d_in[0];
  const float* embed_w  = (const float*)d_in[1];
  const float* embed_b  = (const float*)d_in[2];
  const float* reg_w    = (const float*)d_in[3];
  const float* reg_b    = (const float*)d_in[4];
  const float* ea_w     = (const float*)d_in[5];
  const float* ea_b     = (const float*)d_in[6];
  const float* da_w     = (const float*)d_in[7];
  const float* da_b     = (const float*)d_in[8];
  const float* e2g_w    = (const float*)d_in[9];
  const float* e2g_b    = (const float*)d_in[10];
  const float* e2d_w    = (const float*)d_in[11];
  const float* e2d_b    = (const float*)d_in[12];
  const float* gh2i_w   = (const float*)d_in[13];
  const float* gh2i_b   = (const float*)d_in[14];
  const float* dh2i_w   = (const float*)d_in[15];
  const float* dh2i_b   = (const float*)d_in[16];
  const float* gh2t_w   = (const float*)d_in[17];
  const float* gh2t_b   = (const float*)d_in[18];
  const float* g2e_w    = (const float*)d_in[19];
  const float* g2e_b    = (const float*)d_in[20];
  const float* g2d_w    = (const float*)d_in[21];
  const float* g2d_b    = (const float*)d_in[22];
  const float* enc_wih  = (const float*)d_in[23];
  const float* enc_whh  = (const float*)d_in[24];
  const float* enc_bih  = (const float*)d_in[25];
  const float* enc_bhh  = (const float*)d_in[26];
  const float* goal_wih = (const float*)d_in[27];
  const float* goal_whh = (const float*)d_in[28];
  const float* goal_bih = (const float*)d_in[29];
  const float* goal_bhh = (const float*)d_in[30];
  const float* dec_wih  = (const float*)d_in[31];
  const float* dec_whh  = (const float*)d_in[32];
  const float* dec_bih  = (const float*)d_in[33];
  const float* dec_bhh  = (const float*)d_in[34];

  char* ws = (char*)d_ws;
  size_t off = 0;
  auto alloc = [&](size_t bytes) -> char* {
    char* p = ws + off; off += (bytes + 255) & ~(size_t)255; return p;
  };
  const size_t TSZ = 512 * 512;
  // ---- zero region (contiguous): teh_f, teh_hist, gfe_buf
  float* teh_f    = (float*)alloc(TSZ * 4);
  u16*   teh_hist = (u16*)  alloc(9 * TSZ * 2);
  u16*   gfe_buf  = (u16*)  alloc(512 * 128 * 2);
  size_t zero_bytes = off;
  u16*   traj     = (u16*)  alloc((size_t)8 * TSZ * 2);
  u16*   goals_all= (u16*)  alloc((size_t)8 * 6144 * 128 * 2); // [8][12,512,128]
  u16*   gfd      = (u16*)  alloc((size_t)49152 * 128 * 2);    // [8,12,512,128]
  u16*   xctx     = (u16*)  alloc((size_t)12 * 4096 * 128 * 2);
  float* dh_f     = (float*)alloc((size_t)4096 * 512 * 4);
  u16*   dh_b     = (u16*)  alloc((size_t)4096 * 512 * 2);
  u16*   ddi      = (u16*)  alloc((size_t)4096 * 512 * 2);
  u16*   giD      = (u16*)  alloc((size_t)4096 * 1536 * 2);
  u16*   ghD      = (u16*)  alloc((size_t)4096 * 1536 * 2);
  u16*   giE = giD, *ghE = ghD;                                // enc aliases rows 0:512
  u16* enc_wih_t  = (u16*)alloc((size_t)1536 * 640 * 2);
  u16* enc_whh_t  = (u16*)alloc((size_t)1536 * 512 * 2);
  u16* dec_wih_t  = (u16*)alloc((size_t)1536 * 640 * 2);
  u16* dec_whh_t  = (u16*)alloc((size_t)1536 * 512 * 2);
  u16* e2g_t      = (u16*)alloc(128 * 512 * 2);
  u16* e2d_t      = (u16*)alloc(512 * 512 * 2);
  u16* dh2i_t     = (u16*)alloc(512 * 512 * 2);
  u16* head_t     = (u16*)alloc(640 * 128 * 2);   // rows 0-511: gh2t_t, 512-639: g2d_t
  u16* g2e_t      = (u16*)alloc(128 * 128 * 2);
  u16* goal_wih_t = (u16*)alloc(384 * 128 * 2);
  u16* goal_whh_t = (u16*)alloc(384 * 128 * 2);
  u16* gh2i_t     = (u16*)alloc(128 * 128 * 2);
  if (off > ws_size) return;

  float* out_goal = (float*)d_out;
  float* out_dec  = out_goal + (size_t)512 * 8 * 12 * 2;

  hipMemsetAsync(teh_f, 0, zero_bytes, stream);

  // ---- all weight transposes in one dispatch
  TransArgs ta;
  int ntile = 0, ti = 0;
  auto push = [&](const float* in, u16* out, int K, int N) {
    ta.in[ti] = in; ta.out[ti] = out; ta.K[ti] = K; ta.N[ti] = N;
    ta.t0[ti] = ntile; ta.nx[ti] = N / 32;
    ntile += (K / 32) * (N / 32); ti++;
  };
  push(enc_wih, enc_wih_t, 640, 1536);
  push(enc_whh, enc_whh_t, 512, 1536);
  push(dec_wih, dec_wih_t, 640, 1536);
  push(dec_whh, dec_whh_t, 512, 1536);
  push(e2g_w, e2g_t, 512, 128);
  push(e2d_w, e2d_t, 512, 512);
  push(dh2i_w, dh2i_t, 512, 512);
  push(gh2t_w, head_t, 128, 512);
  push(g2d_w, head_t + 512 * 128, 128, 128);
  push(g2e_w, g2e_t, 128, 128);
  push(goal_wih, goal_wih_t, 128, 384);
  push(goal_whh, goal_whh_t, 128, 384);
  push(gh2i_w, gh2i_t, 128, 128);
  transpose_all<<<ntile, 256, 0, stream>>>(ta);

  embed_kernel<<<8192, 256, 0, stream>>>(inp, embed_w, embed_b, traj);

  const int FAR = 1 << 30;

  // ---------------- encoder chain (2 dispatches per step)
  for (int e = 0; e < 8; ++e) {
    GDesc dgi{traj + (size_t)e * TSZ, 512, gfe_buf, 128, 512,
              enc_wih_t, 640, enc_bih, giE, 1536, nullptr,
              nullptr, 0, FAR, 640, 0, 12, 4};
    GDesc dgh{teh_hist + (size_t)e * TSZ, 512, nullptr, 0, FAR,
              enc_whh_t, 512, enc_bhh, ghE, 1536, nullptr,
              nullptr, 0, FAR, 512, 0, 12, 4};
    gemm128<<<dim3(12, 4, 2), 256, 0, stream>>>(dgi, dgh);
    goal_mega<<<32, 1024, 0, stream>>>(giE, ghE, teh_f, teh_hist + (size_t)(e + 1) * TSZ,
                                       e2g_t, e2g_b,
                                       goal_wih_t, goal_whh_t, goal_bih, goal_bhh,
                                       gh2i_t, gh2i_b, g2e_t, g2e_b, ea_w, ea_b,
                                       goals_all + (size_t)e * 6144 * 128, gfe_buf);
  }

  // ---------------- deferred batched encoder sinks
  {
    // fused goal head: out_goal directly from goals (no ghid, no atomics)
    head_reg<<<768, 256, 0, stream>>>(goals_all, head_t, gh2t_b, reg_w, reg_b, out_goal);
    // z=0: g2d -> gfd (M=49152, N=128, K=128); z=1: e2d -> dh (M=4096)
    GDesc dg2d{goals_all, 128, nullptr, 0, FAR,
               head_t + 512 * 128, 128, g2d_b, gfd, 128, nullptr,
               nullptr, 0, FAR, 128, 1, 1, 384};
    GDesc de2d{teh_hist + TSZ, 512, nullptr, 0, FAR,
               e2d_t, 512, e2d_b, dh_b, 512, dh_f,
               nullptr, 0, FAR, 512, 1, 4, 32};
    gemm128<<<dim3(4, 384, 2), 256, 0, stream>>>(dg2d, de2d);
    attn_ctx_all<<<1024, 256, 0, stream>>>(gfd, da_w, da_b, xctx);
    GDesc dd0{dh_b, 512, nullptr, 0, FAR,
              dh2i_t, 512, dh2i_b, ddi, 512, nullptr,
              nullptr, 0, FAR, 512, 1, 4, 32};
    gemm128<<<dim3(4, 32, 1), 256, 0, stream>>>(dd0, dd0);
  }

  // ---------------- batched decoder (2 dispatches per step)
  for (int td = 0; td < 12; ++td) {
    GDesc dgi{xctx + (size_t)td * 4096 * 128, 128, ddi, 512, 128,
              dec_wih_t, 640, dec_bih, giD, 1536, nullptr,
              nullptr, 0, FAR, 640, 0, 12, 32};
    GDesc dgh{dh_b, 512, nullptr, 0, FAR,
              dec_whh_t, 512, dec_bhh, ghD, 1536, nullptr,
              nullptr, 0, FAR, 512, 0, 12, 32};
    gemm128<<<dim3(12, 32, 2), 256, 0, stream>>>(dgi, dgh);
    gru_dh2i_reg<<<256, 1024, 0, stream>>>(giD, ghD, dh_f, dh_b, dh2i_t, dh2i_b, ddi,
                                           reg_w, reg_b, out_dec, td);
  }
}

// Round 8
// 1276.834 us; speedup vs baseline: 1.1444x; 1.0302x over previous
//
#include <hip/hip_runtime.h>

// SGNet on MI355X. fp32 in/out, internal bf16 MFMA pipeline, fp32 master GRU
// states. Round-8: head_reg with 4 M-tiles/wave (ILP + 4x L2 reuse);
// goal_mega phase-1 wave specialization (gi vs gh waves, halves A-frag LDS
// reads) and uint4 goals stores issued in phase 3.

typedef unsigned short u16;
typedef __attribute__((ext_vector_type(8))) short bf16x8;
typedef __attribute__((ext_vector_type(4))) float f32x4;

static __device__ __forceinline__ float b2f(u16 u) {
  union { float f; unsigned int i; } x; x.i = ((unsigned int)u) << 16; return x.f;
}
static __device__ __forceinline__ u16 f2b(float f) {
  unsigned int u = __float_as_uint(f);
  unsigned int r = (u + 0x7FFFu + ((u >> 16) & 1u)) >> 16;
  return (u16)r;
}
static __device__ __forceinline__ float fsig(float x) {
  return __fdividef(1.f, 1.f + __expf(-x));
}
static __device__ __forceinline__ float ftanh(float x) {
  return 1.f - __fdividef(2.f, __expf(2.f * x) + 1.f);
}

// ---------------------------------------------------------------- all transposes, one dispatch
struct TransArgs {
  const float* in[13];
  u16* out[13];
  int K[13], N[13], t0[13], nx[13];
};

__global__ __launch_bounds__(256) void transpose_all(TransArgs ta) {
  int bid = blockIdx.x;
  int i = 0;
  for (int k = 1; k < 13; k++) if (bid >= ta.t0[k]) i = k;
  const float* in = ta.in[i];
  u16* out = ta.out[i];
  int K = ta.K[i], N = ta.N[i];
  int local = bid - ta.t0[i];
  int nx = ta.nx[i];
  int tx = local % nx, ty = local / nx;
  __shared__ u16 tbuf[32][33];
  int n0 = tx * 32, k0 = ty * 32;
  int x = threadIdx.x & 31, y = threadIdx.x >> 5;  // 32 x 8
  for (int q = 0; q < 4; q++) tbuf[y + 8 * q][x] = f2b(in[(size_t)(k0 + y + 8 * q) * N + n0 + x]);
  __syncthreads();
  for (int q = 0; q < 4; q++) out[(size_t)(n0 + y + 8 * q) * K + k0 + x] = tbuf[x][y + 8 * q];
}

// ---------------------------------------------------------------- embed (K=6)
__global__ __launch_bounds__(256) void embed_kernel(const float* __restrict__ inp,
                                                    const float* __restrict__ w,
                                                    const float* __restrict__ bias,
                                                    u16* __restrict__ traj) {
  int t = blockIdx.x * 256 + threadIdx.x;             // 8*512*512
  int h = t & 511, b = (t >> 9) & 511, e = t >> 18;
  float acc = bias[h];
  for (int i = 0; i < 6; i++) acc += inp[(b * 8 + e) * 6 + i] * w[i * 512 + h];
  traj[((e * 512) + b) * 512 + h] = f2b(fmaxf(acc, 0.f));
}

// ---------------------------------------------------------------- 128-tile MFMA GEMM
struct GDesc {
  const u16* A; int lda;
  const u16* A2; int lda2; int asplit;
  const u16* W; int ldw;
  const float* bias;
  u16* Cb; int ldc;
  float* Cf;
  u16* Cb2; int ldc2; int route_n;
  int K; int relu; int nblk; int mblk;
};

__global__ __launch_bounds__(256) void gemm128(GDesc d0, GDesc d1) {
  GDesc d = (blockIdx.z == 0) ? d0 : d1;
  if ((int)blockIdx.x >= d.nblk || (int)blockIdx.y >= d.mblk) return;
  __shared__ u16 As[128][72];   // 144B row (16B-aligned); 2-way banks (free)
  __shared__ u16 Bs[128][72];
  int tid = threadIdx.x;
  int m0 = blockIdx.y * 128, n0 = blockIdx.x * 128;
  int lane = tid & 63, wave = tid >> 6;
  int wr = wave >> 1, wc = wave & 1;
  int mrow = lane & 15, kq = (lane >> 4) * 8;
  int srow = tid >> 3, scol = (tid & 7) * 8;
  f32x4 acc[4][4] = {};

  for (int k0 = 0; k0 < d.K; k0 += 64) {
    const u16* Asrc; int Alda, kk;
    if (k0 < d.asplit) { Asrc = d.A; Alda = d.lda; kk = k0; }
    else               { Asrc = d.A2; Alda = d.lda2; kk = k0 - d.asplit; }
    __syncthreads();
#pragma unroll
    for (int p = 0; p < 4; p++) {
      int r = srow + p * 32;
      *(uint4*)&As[r][scol] = *(const uint4*)&Asrc[(size_t)(m0 + r) * Alda + kk + scol];
      *(uint4*)&Bs[r][scol] = *(const uint4*)&d.W[(size_t)(n0 + r) * d.ldw + k0 + scol];
    }
    __syncthreads();
#pragma unroll
    for (int ks = 0; ks < 2; ks++) {
      bf16x8 af[4], bf[4];
#pragma unroll
      for (int i = 0; i < 4; i++) {
        af[i] = *(const bf16x8*)&As[wr * 64 + i * 16 + mrow][ks * 32 + kq];
        bf[i] = *(const bf16x8*)&Bs[wc * 64 + i * 16 + mrow][ks * 32 + kq];
      }
#pragma unroll
      for (int i = 0; i < 4; i++)
#pragma unroll
        for (int j = 0; j < 4; j++)
          acc[i][j] = __builtin_amdgcn_mfma_f32_16x16x32_bf16(af[i], bf[j], acc[i][j], 0, 0, 0);
    }
  }
  int col = lane & 15, rq = (lane >> 4) * 4;
#pragma unroll
  for (int j = 0; j < 4; j++) {
    int n = n0 + wc * 64 + j * 16 + col;
    float bv = d.bias ? d.bias[n] : 0.f;
    bool r2 = (n >= d.route_n);
    u16* cb = r2 ? d.Cb2 : d.Cb;
    int ldc = r2 ? d.ldc2 : d.ldc;
    int nn = r2 ? n - d.route_n : n;
#pragma unroll
    for (int i = 0; i < 4; i++)
#pragma unroll
      for (int r = 0; r < 4; r++) {
        int m = m0 + wr * 64 + i * 16 + rq + r;
        float v = acc[i][j][r] + bv;
        if (d.relu) v = fmaxf(v, 0.f);
        cb[(size_t)m * ldc + nn] = f2b(v);
        if (d.Cf) d.Cf[(size_t)m * d.ldc + n] = v;
      }
  }
}

// ---------------------------------------------------------------- fused goal head
// Wave owns 64 rows (4 M-tiles); each B-tile load feeds 4 independent MFMA
// chains (ILP + 4x L2 reuse of gh2t). Sweeps 32 n-tiles, contracting each
// relu'd tile with reg_w immediately. 192 blocks x 4 waves.
__global__ __launch_bounds__(256) void head_reg(const u16* __restrict__ goals,   // [49152,128]
                                                const u16* __restrict__ w_t,     // [512,128] gh2t_t
                                                const float* __restrict__ wb,    // [512]
                                                const float* __restrict__ rw,    // [512,2]
                                                const float* __restrict__ rb,    // [2]
                                                float* __restrict__ out) {
  int tid = threadIdx.x;
  int lane = tid & 63, wave = tid >> 6;
  int rbase = (blockIdx.x * 4 + wave) * 64;
  int mrow = lane & 15, kq = (lane >> 4) * 8;
  int col = lane & 15, rq4 = (lane >> 4) * 4;
  bf16x8 a[4][4];
#pragma unroll
  for (int q = 0; q < 4; q++)
#pragma unroll
    for (int ks = 0; ks < 4; ks++)
      a[q][ks] = *(const bf16x8*)&goals[(size_t)(rbase + q * 16 + mrow) * 128 + ks * 32 + kq];
  float pr0[4][4] = {}, pr1[4][4] = {};
  for (int j = 0; j < 32; j++) {
    bf16x8 b[4];
#pragma unroll
    for (int ks = 0; ks < 4; ks++)
      b[ks] = *(const bf16x8*)&w_t[(size_t)(j * 16 + mrow) * 128 + ks * 32 + kq];
    f32x4 acc[4] = {};
#pragma unroll
    for (int ks = 0; ks < 4; ks++)
#pragma unroll
      for (int q = 0; q < 4; q++)
        acc[q] = __builtin_amdgcn_mfma_f32_16x16x32_bf16(a[q][ks], b[ks], acc[q], 0, 0, 0);
    int n = j * 16 + col;
    float bv = wb[n];
    float rw0 = rw[n * 2], rw1 = rw[n * 2 + 1];
#pragma unroll
    for (int q = 0; q < 4; q++)
#pragma unroll
      for (int r = 0; r < 4; r++) {
        float v = fmaxf(acc[q][r] + bv, 0.f);
        pr0[q][r] += v * rw0;
        pr1[q][r] += v * rw1;
      }
  }
#pragma unroll
  for (int q = 0; q < 4; q++)
#pragma unroll
    for (int r = 0; r < 4; r++)
#pragma unroll
      for (int o = 1; o < 16; o <<= 1) {
        pr0[q][r] += __shfl_xor(pr0[q][r], o);
        pr1[q][r] += __shfl_xor(pr1[q][r], o);
      }
  if (col == 0) {
#pragma unroll
    for (int q = 0; q < 4; q++)
#pragma unroll
      for (int r = 0; r < 4; r++) {
        int m = rbase + q * 16 + rq4 + r;       // (e*12+t)*512 + b
        int e = m / 6144; int rem = m - e * 6144;
        int t = rem >> 9; int b = rem & 511;
        float* o = out + ((size_t)(b * 8 + e) * 12 + t) * 2;
        o[0] = pr0[q][r] + rb[0];
        o[1] = pr1[q][r] + rb[1];
      }
  }
}

// ---------------------------------------------------------------- decoder GRU + reg head + dh2i fused
__global__ __launch_bounds__(1024) void gru_dh2i_reg(const u16* __restrict__ gi,
                                                     const u16* __restrict__ gh,
                                                     float* __restrict__ hf,
                                                     u16* __restrict__ hb,
                                                     const u16* __restrict__ w_t,   // [512,512]
                                                     const float* __restrict__ wb,  // [512]
                                                     u16* __restrict__ ddi,
                                                     const float* __restrict__ rw,
                                                     const float* __restrict__ rb,
                                                     float* __restrict__ out, int td) {
  __shared__ u16 dhs[16][520];   // stride 1040B -> 4-bank shift/row, 2-way (free)
  __shared__ u16 dds[16][520];
  int tid = threadIdx.x;
  int lane = tid & 63, wave = tid >> 6;
  int r0 = blockIdx.x * 16;
  // ---- phase A: pointwise GRU, wave per row
  {
    int r = r0 + wave;
    int j8 = lane * 8;
    size_t base = (size_t)r * 1536 + j8;
    uint4 ir4 = *(const uint4*)&gi[base];
    uint4 iz4 = *(const uint4*)&gi[base + 512];
    uint4 in4 = *(const uint4*)&gi[base + 1024];
    uint4 hr4 = *(const uint4*)&gh[base];
    uint4 hz4 = *(const uint4*)&gh[base + 512];
    uint4 hn4 = *(const uint4*)&gh[base + 1024];
    const u16* irp = (const u16*)&ir4; const u16* izp = (const u16*)&iz4;
    const u16* inp = (const u16*)&in4; const u16* hrp = (const u16*)&hr4;
    const u16* hzp = (const u16*)&hz4; const u16* hnp = (const u16*)&hn4;
    size_t hoff = (size_t)r * 512 + j8;
    float hv[8];
    *(float4*)&hv[0] = *(const float4*)&hf[hoff];
    *(float4*)&hv[4] = *(const float4*)&hf[hoff + 4];
    u16 hbv[8];
    float p0 = 0.f, p1 = 0.f;
    for (int j = 0; j < 8; j++) {
      float rr = fsig(b2f(irp[j]) + b2f(hrp[j]));
      float zz = fsig(b2f(izp[j]) + b2f(hzp[j]));
      float nn = ftanh(b2f(inp[j]) + rr * b2f(hnp[j]));
      float ho = (1.f - zz) * nn + zz * hv[j];
      hv[j] = ho; hbv[j] = f2b(ho);
      p0 += ho * rw[(j8 + j) * 2];
      p1 += ho * rw[(j8 + j) * 2 + 1];
    }
    *(float4*)&hf[hoff] = *(const float4*)&hv[0];
    *(float4*)&hf[hoff + 4] = *(const float4*)&hv[4];
    *(uint4*)&hb[hoff] = *(const uint4*)&hbv[0];
    *(uint4*)&dhs[wave][j8] = *(const uint4*)&hbv[0];
    for (int o = 32; o; o >>= 1) { p0 += __shfl_down(p0, o); p1 += __shfl_down(p1, o); }
    if (lane == 0) {
      int e = r >> 9, b = r & 511;
      size_t off = ((size_t)(b * 8 + e) * 12 + td) * 2;
      out[off] = p0 + rb[0];
      out[off + 1] = p1 + rb[1];
    }
  }
  __syncthreads();
  // ---- phase B: ddi = relu(dh @ dh2i^T + b), 16 waves x 2 tiles of N=512
  int mrow = lane & 15, kq = (lane >> 4) * 8, rq4 = (lane >> 4) * 4;
#pragma unroll
  for (int q = 0; q < 2; q++) {
    int n0 = (wave * 2 + q) * 16;
    f32x4 acc = {};
#pragma unroll
    for (int ks = 0; ks < 16; ks++) {
      bf16x8 a = *(const bf16x8*)&dhs[mrow][ks * 32 + kq];
      bf16x8 bfr = *(const bf16x8*)&w_t[(size_t)(n0 + mrow) * 512 + ks * 32 + kq];
      acc = __builtin_amdgcn_mfma_f32_16x16x32_bf16(a, bfr, acc, 0, 0, 0);
    }
    float bv = wb[n0 + mrow];
#pragma unroll
    for (int x = 0; x < 4; x++)
      dds[rq4 + x][n0 + mrow] = f2b(fmaxf(acc[x] + bv, 0.f));
  }
  __syncthreads();
  // ---- phase C: coalesced store
  int rr = tid >> 6, c8 = (tid & 63) * 8;
  *(uint4*)&ddi[(size_t)(r0 + rr) * 512 + c8] = *(const uint4*)&dds[rr][c8];
}

// ---------------------------------------------------------------- goal_mega
// Phase-1 wave specialization: waves 0-7 compute gi-gates (read only gib),
// waves 8-15 gh-gates (read only ghb). goals emitted as uint4 in phase 3.
__global__ __launch_bounds__(1024) void goal_mega(const u16* __restrict__ gi_g,     // [512,1536]
                                                  const u16* __restrict__ gh_g,     // [512,1536]
                                                  float* __restrict__ teh_f,        // [512,512] fp32 master
                                                  u16* __restrict__ teh_out,        // [512,512] bf16 hist slot
                                                  const u16* __restrict__ e2g_t,    // [128,512]
                                                  const float* __restrict__ e2g_b,  // [128]
                                                  const u16* __restrict__ wih_t,    // [384,128]
                                                  const u16* __restrict__ whh_t,    // [384,128]
                                                  const float* __restrict__ bih,    // [384]
                                                  const float* __restrict__ bhh,    // [384]
                                                  const u16* __restrict__ g2i_t,    // [128,128]
                                                  const float* __restrict__ g2i_b,  // [128]
                                                  const u16* __restrict__ g2e_t,    // [128,128]
                                                  const float* __restrict__ g2e_b,  // [128]
                                                  const float* __restrict__ eaw,    // [128]
                                                  const float* __restrict__ eab,    // [1]
                                                  u16* __restrict__ goals,          // [12,512,128] e-slice
                                                  u16* __restrict__ gfe_out) {      // [512,128]
  __shared__ float ghf[16][128];
  __shared__ u16   ghb[16][136];
  __shared__ u16   gib[16][136];
  __shared__ float gi3[16][388];
  __shared__ float gh3[16][388];
  __shared__ u16   gfe_l[12][16][128];
  __shared__ u16   tehb[16][520];
  int tid = threadIdx.x;
  int r0 = blockIdx.x * 16;
  int lane = tid & 63, wave = tid >> 6;       // 16 waves
  int mrow = lane & 15, kq = (lane >> 4) * 8;
  int rq4 = (lane >> 4) * 4;

  // phase-1 B-fragments: wave w<8 -> gi tiles {w, w+8, w+16}; w>=8 -> gh tiles
  bool isI = (wave < 8);
  int tbase = isI ? wave : wave - 8;
  bf16x8 Bf[3][4];
  float  bias1[3];
  int    n0s[3];
#pragma unroll
  for (int i = 0; i < 3; i++) {
    int n0 = (tbase + 8 * i) * 16;
    n0s[i] = n0;
    const u16* Wt = isI ? wih_t : whh_t;
#pragma unroll
    for (int ks = 0; ks < 4; ks++)
      Bf[i][ks] = *(const bf16x8*)&Wt[(n0 + mrow) * 128 + ks * 32 + kq];
    bias1[i] = (isI ? bih : bhh)[n0 + mrow];
  }
  // phase-3 fragments: waves 0-7 -> g2i, waves 8-15 -> g2e
  bf16x8 Gf[4];
  float bias3;
  {
    const u16* W3 = isI ? g2i_t : g2e_t;
    const float* B3 = isI ? g2i_b : g2e_b;
    int n0 = (wave & 7) * 16;
#pragma unroll
    for (int ks = 0; ks < 4; ks++)
      Gf[ks] = *(const bf16x8*)&W3[(n0 + mrow) * 128 + ks * 32 + kq];
    bias3 = B3[n0 + mrow];
  }

  // zero gib
  {
    u16* gz = &gib[0][0];
    for (int idx = tid; idx < 16 * 136; idx += 1024) gz[idx] = 0;
  }

  // prologue GRU: wave per row (row = wave), 8 elems/lane
  {
    int r = wave;
    int j8 = lane * 8;
    int grow = r0 + r;
    size_t base = (size_t)grow * 1536 + j8;
    uint4 ir4 = *(const uint4*)&gi_g[base];
    uint4 iz4 = *(const uint4*)&gi_g[base + 512];
    uint4 in4 = *(const uint4*)&gi_g[base + 1024];
    uint4 hr4 = *(const uint4*)&gh_g[base];
    uint4 hz4 = *(const uint4*)&gh_g[base + 512];
    uint4 hn4 = *(const uint4*)&gh_g[base + 1024];
    const u16* irp = (const u16*)&ir4; const u16* izp = (const u16*)&iz4;
    const u16* inp = (const u16*)&in4; const u16* hrp = (const u16*)&hr4;
    const u16* hzp = (const u16*)&hz4; const u16* hnp = (const u16*)&hn4;
    size_t hoff = (size_t)grow * 512 + j8;
    float hv[8];
    *(float4*)&hv[0] = *(const float4*)&teh_f[hoff];
    *(float4*)&hv[4] = *(const float4*)&teh_f[hoff + 4];
    u16 hbv[8];
    for (int j = 0; j < 8; j++) {
      float rr = fsig(b2f(irp[j]) + b2f(hrp[j]));
      float zz = fsig(b2f(izp[j]) + b2f(hzp[j]));
      float nn = ftanh(b2f(inp[j]) + rr * b2f(hnp[j]));
      float ho = (1.f - zz) * nn + zz * hv[j];
      hv[j] = ho; hbv[j] = f2b(ho);
    }
    *(float4*)&teh_f[hoff] = *(const float4*)&hv[0];
    *(float4*)&teh_f[hoff + 4] = *(const float4*)&hv[4];
    *(uint4*)&teh_out[hoff] = *(const uint4*)&hbv[0];
    *(uint4*)&tehb[r][j8] = *(const uint4*)&hbv[0];
  }
  __syncthreads();

  // e2g: gh0[16][128] = relu(tehb @ e2g_t^T + b), waves 0-7
  if (wave < 8) {
    int n0 = wave * 16;
    f32x4 acc = {};
#pragma unroll
    for (int ks = 0; ks < 16; ks++) {
      bf16x8 a = *(const bf16x8*)&tehb[mrow][ks * 32 + kq];
      bf16x8 b = *(const bf16x8*)&e2g_t[(size_t)(n0 + mrow) * 512 + ks * 32 + kq];
      acc = __builtin_amdgcn_mfma_f32_16x16x32_bf16(a, b, acc, 0, 0, 0);
    }
    int n = n0 + mrow;
    float bv = e2g_b[n];
#pragma unroll
    for (int r = 0; r < 4; r++) {
      float v = fmaxf(acc[r] + bv, 0.f);
      int m = rq4 + r;
      ghf[m][n] = v;
      ghb[m][n] = f2b(v);
    }
  }
  __syncthreads();

  for (int t = 0; t < 12; t++) {
    // phase 1: wave-specialized gate GEMMs (4 A-frag reads per wave)
    bf16x8 ag[4];
#pragma unroll
    for (int ks = 0; ks < 4; ks++)
      ag[ks] = isI ? *(const bf16x8*)&gib[mrow][ks * 32 + kq]
                   : *(const bf16x8*)&ghb[mrow][ks * 32 + kq];
    float* G = isI ? &gi3[0][0] : &gh3[0][0];
#pragma unroll
    for (int i = 0; i < 3; i++) {
      f32x4 acc = {};
#pragma unroll
      for (int ks = 0; ks < 4; ks++)
        acc = __builtin_amdgcn_mfma_f32_16x16x32_bf16(ag[ks], Bf[i][ks], acc, 0, 0, 0);
      int n = n0s[i] + mrow;
#pragma unroll
      for (int r = 0; r < 4; r++)
        G[(rq4 + r) * 388 + n] = acc[r] + bias1[i];
    }
    __syncthreads();
    // phase 2: pointwise GRU (LDS only; goals stored in phase 3)
    for (int idx = tid; idx < 2048; idx += 1024) {
      int m = idx >> 7, j = idx & 127;
      float rr = fsig(gi3[m][j] + gh3[m][j]);
      float zz = fsig(gi3[m][128 + j] + gh3[m][128 + j]);
      float nn = ftanh(gi3[m][256 + j] + rr * gh3[m][256 + j]);
      float h = ghf[m][j];
      float ho = (1.f - zz) * nn + zz * h;
      ghf[m][j] = ho;
      ghb[m][j] = f2b(ho);
    }
    __syncthreads();
    // phase 3: goals uint4 store (waves 0-3, overlaps MFMA) +
    //          waves 0-7: gib = relu(gh@g2i+b); waves 8-15: gfe_l[t] = relu(gh@g2e+b)
    if (wave < 4) {
      int idx = wave * 64 + lane;           // 256 lanes cover 16x128
      int row = idx >> 4, c8 = (idx & 15) * 8;
      uint4 v = *(const uint4*)&ghb[row][c8];
      *(uint4*)&goals[(size_t)(t * 512 + r0 + row) * 128 + c8] = v;
    }
    {
      f32x4 acc = {};
#pragma unroll
      for (int ks = 0; ks < 4; ks++) {
        bf16x8 a = *(const bf16x8*)&ghb[mrow][ks * 32 + kq];
        acc = __builtin_amdgcn_mfma_f32_16x16x32_bf16(a, Gf[ks], acc, 0, 0, 0);
      }
      int n = (wave & 7) * 16 + mrow;
      if (isI) {
#pragma unroll
        for (int r = 0; r < 4; r++)
          gib[rq4 + r][n] = f2b(fmaxf(acc[r] + bias3, 0.f));
      } else {
#pragma unroll
        for (int r = 0; r < 4; r++)
          gfe_l[t][rq4 + r][n] = f2b(fmaxf(acc[r] + bias3, 0.f));
      }
    }
    __syncthreads();
  }

  // encoder attention (wave w -> row w), write gfe carry
  {
    int m = wave;
    float w0 = eaw[lane], w1 = eaw[lane + 64];
    float eb = eab[0];
    float v0[12], v1[12], lg[12];
#pragma unroll
    for (int t = 0; t < 12; t++) {
      float a = b2f(gfe_l[t][m][lane]);
      float c = b2f(gfe_l[t][m][lane + 64]);
      v0[t] = a; v1[t] = c;
      float p = ftanh(a) * w0 + ftanh(c) * w1;
      for (int o = 32; o; o >>= 1) p += __shfl_xor(p, o);
      lg[t] = fmaxf(p + eb, 0.f);
    }
    float mx = lg[0];
#pragma unroll
    for (int t = 1; t < 12; t++) mx = fmaxf(mx, lg[t]);
    float s = 0.f;
#pragma unroll
    for (int t = 0; t < 12; t++) { lg[t] = __expf(lg[t] - mx); s += lg[t]; }
    float inv = __fdividef(1.f, s);
    float c0 = 0.f, c1 = 0.f;
#pragma unroll
    for (int t = 0; t < 12; t++) { c0 += lg[t] * inv * v0[t]; c1 += lg[t] * inv * v1[t]; }
    gfe_out[(r0 + m) * 128 + lane] = f2b(c0);
    gfe_out[(r0 + m) * 128 + lane + 64] = f2b(c1);
  }
}

// ---------------------------------------------------------------- decoder ctx, suffix softmax
__global__ __launch_bounds__(256) void attn_ctx_all(const u16* __restrict__ gfd,  // [8,12,512,128]
                                                    const float* __restrict__ daw,
                                                    const float* __restrict__ dab,
                                                    u16* __restrict__ xctx) {      // [12,4096,128]
  int row = (blockIdx.x * 256 + threadIdx.x) >> 6;   // e*512 + b
  int lane = threadIdx.x & 63;
  int e = row >> 9, b = row & 511;
  float w0 = daw[lane], w1 = daw[lane + 64];
  float bias = dab[0];
  float v0[12], v1[12], lg[12];
#pragma unroll
  for (int s = 0; s < 12; s++) {
    size_t o = ((size_t)(e * 12 + s) * 512 + b) * 128;
    float a = b2f(gfd[o + lane]);
    float c = b2f(gfd[o + 64 + lane]);
    v0[s] = a; v1[s] = c;
    float p = ftanh(a) * w0 + ftanh(c) * w1;
    for (int o2 = 32; o2; o2 >>= 1) p += __shfl_xor(p, o2);
    lg[s] = fmaxf(p + bias, 0.f);
  }
  float base = fmaxf(bias, 0.f);
  float m = base;
#pragma unroll
  for (int s = 0; s < 12; s++) m = fmaxf(m, lg[s]);
  float eb = __expf(base - m);
  float el[12];
#pragma unroll
  for (int s = 0; s < 12; s++) el[s] = __expf(lg[s] - m);
  float S0 = 0.f, S1 = 0.f, sufE = 0.f;
#pragma unroll
  for (int td = 11; td >= 0; td--) {
    sufE += el[td];
    S0 += el[td] * v0[td];
    S1 += el[td] * v1[td];
    float inv = __fdividef(1.f, (float)td * eb + sufE);
    size_t o = ((size_t)td * 4096 + row) * 128;
    xctx[o + lane] = f2b(S0 * inv);
    xctx[o + lane + 64] = f2b(S1 * inv);
  }
}

// ================================================================ host
extern "C" void kernel_launch(void* const* d_in, const int* in_sizes, int n_in,
                              void* d_out, int out_size, void* d_ws, size_t ws_size,
                              hipStream_t stream) {
  const float* inp      = (const float*)d_in[0];
  const float* embed_w  = (const float*)d_in[1];
  const float* embed_b  = (const float*)d_in[2];
  const float* reg_w    = (const float*)d_in[3];
  const float* reg_b    = (const float*)d_in[4];
  const float* ea_w     = (const float*)d_in[5];
  const float* ea_b     = (const float*)d_in[6];
  const float* da_w     = (const float*)d_in[7];
  const float* da_b     = (const float*)d_in[8];
  const float* e2g_w    = (const float*)d_in[9];
  const float* e2g_b    = (const float*)d_in[10];
  const float* e2d_w    = (const float*)d_in[11];
  const float* e2d_b    = (const float*)d_in[12];
  const float* gh2i_w   = (const float*)d_in[13];
  const float* gh2i_b   = (const float*)d_in[14];
  const float* dh2i_w   = (const float*)d_in[15];
  const float* dh2i_b   = (const float*)d_in[16];
  const float* gh2t_w   = (const float*)d_in[17];
  const float* gh2t_b   = (const float*)d_in[18];
  const float* g2e_w    = (const float*)d_in[19];
  const float* g2e_b    = (const float*)d_in[20];
  const float* g2d_w    = (const float*)d_in[21];
  const float* g2d_b    = (const float*)d_in[22];
  const float* enc_wih  = (const float*)d_in[23];
  const float* enc_whh  = (const float*)d_in[24];
  const float* enc_bih  = (const float*)d_in[25];
  const float* enc_bhh  = (const float*)d_in[26];
  const float* goal_wih = (const float*)d_in[27];
  const float* goal_whh = (const float*)d_in[28];
  const float* goal_bih = (const float*)d_in[29];
  const float* goal_bhh = (const float*)d_in[30];
  const float* dec_wih  = (const float*)d_in[31];
  const float* dec_whh  = (const float*)d_in[32];
  const float* dec_bih  = (const float*)d_in[33];
  const float* dec_bhh  = (const float*)d_in[34];

  char* ws = (char*)d_ws;
  size_t off = 0;
  auto alloc = [&](size_t bytes) -> char* {
    char* p = ws + off; off += (bytes + 255) & ~(size_t)255; return p;
  };
  const size_t TSZ = 512 * 512;
  // ---- zero region (contiguous): teh_f, teh_hist, gfe_buf
  float* teh_f    = (float*)alloc(TSZ * 4);
  u16*   teh_hist = (u16*)  alloc(9 * TSZ * 2);
  u16*   gfe_buf  = (u16*)  alloc(512 * 128 * 2);
  size_t zero_bytes = off;
  u16*   traj     = (u16*)  alloc((size_t)8 * TSZ * 2);
  u16*   goals_all= (u16*)  alloc((size_t)8 * 6144 * 128 * 2); // [8][12,512,128]
  u16*   gfd      = (u16*)  alloc((size_t)49152 * 128 * 2);    // [8,12,512,128]
  u16*   xctx     = (u16*)  alloc((size_t)12 * 4096 * 128 * 2);
  float* dh_f     = (float*)alloc((size_t)4096 * 512 * 4);
  u16*   dh_b     = (u16*)  alloc((size_t)4096 * 512 * 2);
  u16*   ddi      = (u16*)  alloc((size_t)4096 * 512 * 2);
  u16*   giD      = (u16*)  alloc((size_t)4096 * 1536 * 2);
  u16*   ghD      = (u16*)  alloc((size_t)4096 * 1536 * 2);
  u16*   giE = giD, *ghE = ghD;                                // enc aliases rows 0:512
  u16* enc_wih_t  = (u16*)alloc((size_t)1536 * 640 * 2);
  u16* enc_whh_t  = (u16*)alloc((size_t)1536 * 512 * 2);
  u16* dec_wih_t  = (u16*)alloc((size_t)1536 * 640 * 2);
  u16* dec_whh_t  = (u16*)alloc((size_t)1536 * 512 * 2);
  u16* e2g_t      = (u16*)alloc(128 * 512 * 2);
  u16* e2d_t      = (u16*)alloc(512 * 512 * 2);
  u16* dh2i_t     = (u16*)alloc(512 * 512 * 2);
  u16* head_t     = (u16*)alloc(640 * 128 * 2);   // rows 0-511: gh2t_t, 512-639: g2d_t
  u16* g2e_t      = (u16*)alloc(128 * 128 * 2);
  u16* goal_wih_t = (u16*)alloc(384 * 128 * 2);
  u16* goal_whh_t = (u16*)alloc(384 * 128 * 2);
  u16* gh2i_t     = (u16*)alloc(128 * 128 * 2);
  if (off > ws_size) return;

  float* out_goal = (float*)d_out;
  float* out_dec  = out_goal + (size_t)512 * 8 * 12 * 2;

  hipMemsetAsync(teh_f, 0, zero_bytes, stream);

  // ---- all weight transposes in one dispatch
  TransArgs ta;
  int ntile = 0, ti = 0;
  auto push = [&](const float* in, u16* out, int K, int N) {
    ta.in[ti] = in; ta.out[ti] = out; ta.K[ti] = K; ta.N[ti] = N;
    ta.t0[ti] = ntile; ta.nx[ti] = N / 32;
    ntile += (K / 32) * (N / 32); ti++;
  };
  push(enc_wih, enc_wih_t, 640, 1536);
  push(enc_whh, enc_whh_t, 512, 1536);
  push(dec_wih, dec_wih_t, 640, 1536);
  push(dec_whh, dec_whh_t, 512, 1536);
  push(e2g_w, e2g_t, 512, 128);
  push(e2d_w, e2d_t, 512, 512);
  push(dh2i_w, dh2i_t, 512, 512);
  push(gh2t_w, head_t, 128, 512);
  push(g2d_w, head_t + 512 * 128, 128, 128);
  push(g2e_w, g2e_t, 128, 128);
  push(goal_wih, goal_wih_t, 128, 384);
  push(goal_whh, goal_whh_t, 128, 384);
  push(gh2i_w, gh2i_t, 128, 128);
  transpose_all<<<ntile, 256, 0, stream>>>(ta);

  embed_kernel<<<8192, 256, 0, stream>>>(inp, embed_w, embed_b, traj);

  const int FAR = 1 << 30;

  // ---------------- encoder chain (2 dispatches per step)
  for (int e = 0; e < 8; ++e) {
    GDesc dgi{traj + (size_t)e * TSZ, 512, gfe_buf, 128, 512,
              enc_wih_t, 640, enc_bih, giE, 1536, nullptr,
              nullptr, 0, FAR, 640, 0, 12, 4};
    GDesc dgh{teh_hist + (size_t)e * TSZ, 512, nullptr, 0, FAR,
              enc_whh_t, 512, enc_bhh, ghE, 1536, nullptr,
              nullptr, 0, FAR, 512, 0, 12, 4};
    gemm128<<<dim3(12, 4, 2), 256, 0, stream>>>(dgi, dgh);
    goal_mega<<<32, 1024, 0, stream>>>(giE, ghE, teh_f, teh_hist + (size_t)(e + 1) * TSZ,
                                       e2g_t, e2g_b,
                                       goal_wih_t, goal_whh_t, goal_bih, goal_bhh,
                                       gh2i_t, gh2i_b, g2e_t, g2e_b, ea_w, ea_b,
                                       goals_all + (size_t)e * 6144 * 128, gfe_buf);
  }

  // ---------------- deferred batched encoder sinks
  {
    // fused goal head: out_goal directly from goals (no ghid, no atomics)
    head_reg<<<192, 256, 0, stream>>>(goals_all, head_t, gh2t_b, reg_w, reg_b, out_goal);
    // z=0: g2d -> gfd (M=49152, N=128, K=128); z=1: e2d -> dh (M=4096)
    GDesc dg2d{goals_all, 128, nullptr, 0, FAR,
               head_t + 512 * 128, 128, g2d_b, gfd, 128, nullptr,
               nullptr, 0, FAR, 128, 1, 1, 384};
    GDesc de2d{teh_hist + TSZ, 512, nullptr, 0, FAR,
               e2d_t, 512, e2d_b, dh_b, 512, dh_f,
               nullptr, 0, FAR, 512, 1, 4, 32};
    gemm128<<<dim3(4, 384, 2), 256, 0, stream>>>(dg2d, de2d);
    attn_ctx_all<<<1024, 256, 0, stream>>>(gfd, da_w, da_b, xctx);
    GDesc dd0{dh_b, 512, nullptr, 0, FAR,
              dh2i_t, 512, dh2i_b, ddi, 512, nullptr,
              nullptr, 0, FAR, 512, 1, 4, 32};
    gemm128<<<dim3(4, 32, 1), 256, 0, stream>>>(dd0, dd0);
  }

  // ---------------- batched decoder (2 dispatches per step)
  for (int td = 0; td < 12; ++td) {
    GDesc dgi{xctx + (size_t)td * 4096 * 128, 128, ddi, 512, 128,
              dec_wih_t, 640, dec_bih, giD, 1536, nullptr,
              nullptr, 0, FAR, 640, 0, 12, 32};
    GDesc dgh{dh_b, 512, nullptr, 0, FAR,
              dec_whh_t, 512, dec_bhh, ghD, 1536, nullptr,
              nullptr, 0, FAR, 512, 0, 12, 32};
    gemm128<<<dim3(12, 32, 2), 256, 0, stream>>>(dgi, dgh);
    gru_dh2i_reg<<<256, 1024, 0, stream>>>(giD, ghD, dh_f, dh_b, dh2i_t, dh2i_b, ddi,
                                           reg_w, reg_b, out_dec, td);
  }
}

// Round 9
// 1247.372 us; speedup vs baseline: 1.1714x; 1.0236x over previous
//
#include <hip/hip_runtime.h>

// SGNet on MI355X. fp32 in/out, internal bf16 MFMA pipeline, fp32 master GRU
// states. Round-9: goal_mega v2 — register-resident gates & h-state via MFMA
// C-layout tiling (wave w owns gate n-tiles {w,w+8,w+16} of gi AND gh, so
// r/z/n gates of element (m,j) sit in the same lane), ping-pong ghb, 2
// barriers/step, zero LDS gate traffic. Rest unchanged from r8.

typedef unsigned short u16;
typedef __attribute__((ext_vector_type(8))) short bf16x8;
typedef __attribute__((ext_vector_type(4))) float f32x4;

static __device__ __forceinline__ float b2f(u16 u) {
  union { float f; unsigned int i; } x; x.i = ((unsigned int)u) << 16; return x.f;
}
static __device__ __forceinline__ u16 f2b(float f) {
  unsigned int u = __float_as_uint(f);
  unsigned int r = (u + 0x7FFFu + ((u >> 16) & 1u)) >> 16;
  return (u16)r;
}
static __device__ __forceinline__ float fsig(float x) {
  return __fdividef(1.f, 1.f + __expf(-x));
}
static __device__ __forceinline__ float ftanh(float x) {
  return 1.f - __fdividef(2.f, __expf(2.f * x) + 1.f);
}

// ---------------------------------------------------------------- all transposes, one dispatch
struct TransArgs {
  const float* in[13];
  u16* out[13];
  int K[13], N[13], t0[13], nx[13];
};

__global__ __launch_bounds__(256) void transpose_all(TransArgs ta) {
  int bid = blockIdx.x;
  int i = 0;
  for (int k = 1; k < 13; k++) if (bid >= ta.t0[k]) i = k;
  const float* in = ta.in[i];
  u16* out = ta.out[i];
  int K = ta.K[i], N = ta.N[i];
  int local = bid - ta.t0[i];
  int nx = ta.nx[i];
  int tx = local % nx, ty = local / nx;
  __shared__ u16 tbuf[32][33];
  int n0 = tx * 32, k0 = ty * 32;
  int x = threadIdx.x & 31, y = threadIdx.x >> 5;  // 32 x 8
  for (int q = 0; q < 4; q++) tbuf[y + 8 * q][x] = f2b(in[(size_t)(k0 + y + 8 * q) * N + n0 + x]);
  __syncthreads();
  for (int q = 0; q < 4; q++) out[(size_t)(n0 + y + 8 * q) * K + k0 + x] = tbuf[x][y + 8 * q];
}

// ---------------------------------------------------------------- embed (K=6)
__global__ __launch_bounds__(256) void embed_kernel(const float* __restrict__ inp,
                                                    const float* __restrict__ w,
                                                    const float* __restrict__ bias,
                                                    u16* __restrict__ traj) {
  int t = blockIdx.x * 256 + threadIdx.x;             // 8*512*512
  int h = t & 511, b = (t >> 9) & 511, e = t >> 18;
  float acc = bias[h];
  for (int i = 0; i < 6; i++) acc += inp[(b * 8 + e) * 6 + i] * w[i * 512 + h];
  traj[((e * 512) + b) * 512 + h] = f2b(fmaxf(acc, 0.f));
}

// ---------------------------------------------------------------- 128-tile MFMA GEMM
struct GDesc {
  const u16* A; int lda;
  const u16* A2; int lda2; int asplit;
  const u16* W; int ldw;
  const float* bias;
  u16* Cb; int ldc;
  float* Cf;
  u16* Cb2; int ldc2; int route_n;
  int K; int relu; int nblk; int mblk;
};

__global__ __launch_bounds__(256) void gemm128(GDesc d0, GDesc d1) {
  GDesc d = (blockIdx.z == 0) ? d0 : d1;
  if ((int)blockIdx.x >= d.nblk || (int)blockIdx.y >= d.mblk) return;
  __shared__ u16 As[128][72];   // 144B row (16B-aligned); 2-way banks (free)
  __shared__ u16 Bs[128][72];
  int tid = threadIdx.x;
  int m0 = blockIdx.y * 128, n0 = blockIdx.x * 128;
  int lane = tid & 63, wave = tid >> 6;
  int wr = wave >> 1, wc = wave & 1;
  int mrow = lane & 15, kq = (lane >> 4) * 8;
  int srow = tid >> 3, scol = (tid & 7) * 8;
  f32x4 acc[4][4] = {};

  for (int k0 = 0; k0 < d.K; k0 += 64) {
    const u16* Asrc; int Alda, kk;
    if (k0 < d.asplit) { Asrc = d.A; Alda = d.lda; kk = k0; }
    else               { Asrc = d.A2; Alda = d.lda2; kk = k0 - d.asplit; }
    __syncthreads();
#pragma unroll
    for (int p = 0; p < 4; p++) {
      int r = srow + p * 32;
      *(uint4*)&As[r][scol] = *(const uint4*)&Asrc[(size_t)(m0 + r) * Alda + kk + scol];
      *(uint4*)&Bs[r][scol] = *(const uint4*)&d.W[(size_t)(n0 + r) * d.ldw + k0 + scol];
    }
    __syncthreads();
#pragma unroll
    for (int ks = 0; ks < 2; ks++) {
      bf16x8 af[4], bf[4];
#pragma unroll
      for (int i = 0; i < 4; i++) {
        af[i] = *(const bf16x8*)&As[wr * 64 + i * 16 + mrow][ks * 32 + kq];
        bf[i] = *(const bf16x8*)&Bs[wc * 64 + i * 16 + mrow][ks * 32 + kq];
      }
#pragma unroll
      for (int i = 0; i < 4; i++)
#pragma unroll
        for (int j = 0; j < 4; j++)
          acc[i][j] = __builtin_amdgcn_mfma_f32_16x16x32_bf16(af[i], bf[j], acc[i][j], 0, 0, 0);
    }
  }
  int col = lane & 15, rq = (lane >> 4) * 4;
#pragma unroll
  for (int j = 0; j < 4; j++) {
    int n = n0 + wc * 64 + j * 16 + col;
    float bv = d.bias ? d.bias[n] : 0.f;
    bool r2 = (n >= d.route_n);
    u16* cb = r2 ? d.Cb2 : d.Cb;
    int ldc = r2 ? d.ldc2 : d.ldc;
    int nn = r2 ? n - d.route_n : n;
#pragma unroll
    for (int i = 0; i < 4; i++)
#pragma unroll
      for (int r = 0; r < 4; r++) {
        int m = m0 + wr * 64 + i * 16 + rq + r;
        float v = acc[i][j][r] + bv;
        if (d.relu) v = fmaxf(v, 0.f);
        cb[(size_t)m * ldc + nn] = f2b(v);
        if (d.Cf) d.Cf[(size_t)m * d.ldc + n] = v;
      }
  }
}

// ---------------------------------------------------------------- fused goal head (r8 form)
__global__ __launch_bounds__(256) void head_reg(const u16* __restrict__ goals,   // [49152,128]
                                                const u16* __restrict__ w_t,     // [512,128] gh2t_t
                                                const float* __restrict__ wb,    // [512]
                                                const float* __restrict__ rw,    // [512,2]
                                                const float* __restrict__ rb,    // [2]
                                                float* __restrict__ out) {
  int tid = threadIdx.x;
  int lane = tid & 63, wave = tid >> 6;
  int rbase = (blockIdx.x * 4 + wave) * 64;
  int mrow = lane & 15, kq = (lane >> 4) * 8;
  int col = lane & 15, rq4 = (lane >> 4) * 4;
  bf16x8 a[4][4];
#pragma unroll
  for (int q = 0; q < 4; q++)
#pragma unroll
    for (int ks = 0; ks < 4; ks++)
      a[q][ks] = *(const bf16x8*)&goals[(size_t)(rbase + q * 16 + mrow) * 128 + ks * 32 + kq];
  float pr0[4][4] = {}, pr1[4][4] = {};
  for (int j = 0; j < 32; j++) {
    bf16x8 b[4];
#pragma unroll
    for (int ks = 0; ks < 4; ks++)
      b[ks] = *(const bf16x8*)&w_t[(size_t)(j * 16 + mrow) * 128 + ks * 32 + kq];
    f32x4 acc[4] = {};
#pragma unroll
    for (int ks = 0; ks < 4; ks++)
#pragma unroll
      for (int q = 0; q < 4; q++)
        acc[q] = __builtin_amdgcn_mfma_f32_16x16x32_bf16(a[q][ks], b[ks], acc[q], 0, 0, 0);
    int n = j * 16 + col;
    float bv = wb[n];
    float rw0 = rw[n * 2], rw1 = rw[n * 2 + 1];
#pragma unroll
    for (int q = 0; q < 4; q++)
#pragma unroll
      for (int r = 0; r < 4; r++) {
        float v = fmaxf(acc[q][r] + bv, 0.f);
        pr0[q][r] += v * rw0;
        pr1[q][r] += v * rw1;
      }
  }
#pragma unroll
  for (int q = 0; q < 4; q++)
#pragma unroll
    for (int r = 0; r < 4; r++)
#pragma unroll
      for (int o = 1; o < 16; o <<= 1) {
        pr0[q][r] += __shfl_xor(pr0[q][r], o);
        pr1[q][r] += __shfl_xor(pr1[q][r], o);
      }
  if (col == 0) {
#pragma unroll
    for (int q = 0; q < 4; q++)
#pragma unroll
      for (int r = 0; r < 4; r++) {
        int m = rbase + q * 16 + rq4 + r;       // (e*12+t)*512 + b
        int e = m / 6144; int rem = m - e * 6144;
        int t = rem >> 9; int b = rem & 511;
        float* o = out + ((size_t)(b * 8 + e) * 12 + t) * 2;
        o[0] = pr0[q][r] + rb[0];
        o[1] = pr1[q][r] + rb[1];
      }
  }
}

// ---------------------------------------------------------------- decoder GRU + reg head + dh2i fused
__global__ __launch_bounds__(1024) void gru_dh2i_reg(const u16* __restrict__ gi,
                                                     const u16* __restrict__ gh,
                                                     float* __restrict__ hf,
                                                     u16* __restrict__ hb,
                                                     const u16* __restrict__ w_t,   // [512,512]
                                                     const float* __restrict__ wb,  // [512]
                                                     u16* __restrict__ ddi,
                                                     const float* __restrict__ rw,
                                                     const float* __restrict__ rb,
                                                     float* __restrict__ out, int td) {
  __shared__ u16 dhs[16][520];   // stride 1040B -> 4-bank shift/row, 2-way (free)
  __shared__ u16 dds[16][520];
  int tid = threadIdx.x;
  int lane = tid & 63, wave = tid >> 6;
  int r0 = blockIdx.x * 16;
  // ---- phase A: pointwise GRU, wave per row
  {
    int r = r0 + wave;
    int j8 = lane * 8;
    size_t base = (size_t)r * 1536 + j8;
    uint4 ir4 = *(const uint4*)&gi[base];
    uint4 iz4 = *(const uint4*)&gi[base + 512];
    uint4 in4 = *(const uint4*)&gi[base + 1024];
    uint4 hr4 = *(const uint4*)&gh[base];
    uint4 hz4 = *(const uint4*)&gh[base + 512];
    uint4 hn4 = *(const uint4*)&gh[base + 1024];
    const u16* irp = (const u16*)&ir4; const u16* izp = (const u16*)&iz4;
    const u16* inp = (const u16*)&in4; const u16* hrp = (const u16*)&hr4;
    const u16* hzp = (const u16*)&hz4; const u16* hnp = (const u16*)&hn4;
    size_t hoff = (size_t)r * 512 + j8;
    float hv[8];
    *(float4*)&hv[0] = *(const float4*)&hf[hoff];
    *(float4*)&hv[4] = *(const float4*)&hf[hoff + 4];
    u16 hbv[8];
    float p0 = 0.f, p1 = 0.f;
    for (int j = 0; j < 8; j++) {
      float rr = fsig(b2f(irp[j]) + b2f(hrp[j]));
      float zz = fsig(b2f(izp[j]) + b2f(hzp[j]));
      float nn = ftanh(b2f(inp[j]) + rr * b2f(hnp[j]));
      float ho = (1.f - zz) * nn + zz * hv[j];
      hv[j] = ho; hbv[j] = f2b(ho);
      p0 += ho * rw[(j8 + j) * 2];
      p1 += ho * rw[(j8 + j) * 2 + 1];
    }
    *(float4*)&hf[hoff] = *(const float4*)&hv[0];
    *(float4*)&hf[hoff + 4] = *(const float4*)&hv[4];
    *(uint4*)&hb[hoff] = *(const uint4*)&hbv[0];
    *(uint4*)&dhs[wave][j8] = *(const uint4*)&hbv[0];
    for (int o = 32; o; o >>= 1) { p0 += __shfl_down(p0, o); p1 += __shfl_down(p1, o); }
    if (lane == 0) {
      int e = r >> 9, b = r & 511;
      size_t off = ((size_t)(b * 8 + e) * 12 + td) * 2;
      out[off] = p0 + rb[0];
      out[off + 1] = p1 + rb[1];
    }
  }
  __syncthreads();
  // ---- phase B: ddi = relu(dh @ dh2i^T + b), 16 waves x 2 tiles of N=512
  int mrow = lane & 15, kq = (lane >> 4) * 8, rq4 = (lane >> 4) * 4;
#pragma unroll
  for (int q = 0; q < 2; q++) {
    int n0 = (wave * 2 + q) * 16;
    f32x4 acc = {};
#pragma unroll
    for (int ks = 0; ks < 16; ks++) {
      bf16x8 a = *(const bf16x8*)&dhs[mrow][ks * 32 + kq];
      bf16x8 bfr = *(const bf16x8*)&w_t[(size_t)(n0 + mrow) * 512 + ks * 32 + kq];
      acc = __builtin_amdgcn_mfma_f32_16x16x32_bf16(a, bfr, acc, 0, 0, 0);
    }
    float bv = wb[n0 + mrow];
#pragma unroll
    for (int x = 0; x < 4; x++)
      dds[rq4 + x][n0 + mrow] = f2b(fmaxf(acc[x] + bv, 0.f));
  }
  __syncthreads();
  // ---- phase C: coalesced store
  int rr = tid >> 6, c8 = (tid & 63) * 8;
  *(uint4*)&ddi[(size_t)(r0 + rr) * 512 + c8] = *(const uint4*)&dds[rr][c8];
}

// ---------------------------------------------------------------- goal_mega v2
// 8 waves (512 thr), 16 rows/block, 32 blocks. Wave w owns gate n-tiles
// {w, w+8, w+16} of BOTH gi and gh -> r/z/n gates of (m,j) live in the same
// lane; GRU pointwise and fp32 h-state are register-only (C-layout). ghb is
// ping-ponged so gate reads and h writes never race: 2 barriers/step.
__global__ __launch_bounds__(512) void goal_mega(const u16* __restrict__ gi_g,     // [512,1536]
                                                 const u16* __restrict__ gh_g,     // [512,1536]
                                                 float* __restrict__ teh_f,        // [512,512] fp32 master
                                                 u16* __restrict__ teh_out,        // [512,512] bf16 hist
                                                 const u16* __restrict__ e2g_t,    // [128,512]
                                                 const float* __restrict__ e2g_b,  // [128]
                                                 const u16* __restrict__ wih_t,    // [384,128]
                                                 const u16* __restrict__ whh_t,    // [384,128]
                                                 const float* __restrict__ bih,    // [384]
                                                 const float* __restrict__ bhh,    // [384]
                                                 const u16* __restrict__ g2i_t,    // [128,128]
                                                 const float* __restrict__ g2i_b,  // [128]
                                                 const u16* __restrict__ g2e_t,    // [128,128]
                                                 const float* __restrict__ g2e_b,  // [128]
                                                 const float* __restrict__ eaw,    // [128]
                                                 const float* __restrict__ eab,    // [1]
                                                 u16* __restrict__ goals,          // [12,512,128] e-slice
                                                 u16* __restrict__ gfe_out) {      // [512,128]
  __shared__ u16 ghb[2][16][136];   // ping-pong h (bf16)
  __shared__ u16 gib[16][136];
  __shared__ u16 gfe_l[12][16][128];
  __shared__ u16 tehb[16][520];
  int tid = threadIdx.x;
  int r0 = blockIdx.x * 16;
  int lane = tid & 63, wave = tid >> 6;       // 8 waves
  int mrow = lane & 15, kq = (lane >> 4) * 8;
  int rq4 = (lane >> 4) * 4;
  int col = lane & 15;
  int ncol = wave * 16 + col;                 // this wave's C-tile column range

  // gate B-fragments: tiles {w, w+8, w+16} for gi (wih) and gh (whh)
  bf16x8 BfI[3][4], BfH[3][4];
  float bI[3], bH[3];
#pragma unroll
  for (int i = 0; i < 3; i++) {
    int n0 = (wave + 8 * i) * 16;
#pragma unroll
    for (int ks = 0; ks < 4; ks++) {
      BfI[i][ks] = *(const bf16x8*)&wih_t[(n0 + mrow) * 128 + ks * 32 + kq];
      BfH[i][ks] = *(const bf16x8*)&whh_t[(n0 + mrow) * 128 + ks * 32 + kq];
    }
    bI[i] = bih[n0 + col];
    bH[i] = bhh[n0 + col];
  }
  // phase-3 fragments: wave w does g2i tile w and g2e tile w
  bf16x8 GfI[4], GfE[4];
  float bGi, bGe;
  {
    int n0 = wave * 16;
#pragma unroll
    for (int ks = 0; ks < 4; ks++) {
      GfI[ks] = *(const bf16x8*)&g2i_t[(n0 + mrow) * 128 + ks * 32 + kq];
      GfE[ks] = *(const bf16x8*)&g2e_t[(n0 + mrow) * 128 + ks * 32 + kq];
    }
    bGi = g2i_b[n0 + col];
    bGe = g2e_b[n0 + col];
  }

  // zero gib
  {
    u16* gz = &gib[0][0];
    for (int idx = tid; idx < 16 * 136; idx += 512) gz[idx] = 0;
  }

  // prologue encoder GRU: 2 rows per wave
#pragma unroll
  for (int rep = 0; rep < 2; rep++) {
    int r = wave + 8 * rep;
    int j8 = lane * 8;
    int grow = r0 + r;
    size_t base = (size_t)grow * 1536 + j8;
    uint4 ir4 = *(const uint4*)&gi_g[base];
    uint4 iz4 = *(const uint4*)&gi_g[base + 512];
    uint4 in4 = *(const uint4*)&gi_g[base + 1024];
    uint4 hr4 = *(const uint4*)&gh_g[base];
    uint4 hz4 = *(const uint4*)&gh_g[base + 512];
    uint4 hn4 = *(const uint4*)&gh_g[base + 1024];
    const u16* irp = (const u16*)&ir4; const u16* izp = (const u16*)&iz4;
    const u16* inp = (const u16*)&in4; const u16* hrp = (const u16*)&hr4;
    const u16* hzp = (const u16*)&hz4; const u16* hnp = (const u16*)&hn4;
    size_t hoff = (size_t)grow * 512 + j8;
    float hv[8];
    *(float4*)&hv[0] = *(const float4*)&teh_f[hoff];
    *(float4*)&hv[4] = *(const float4*)&teh_f[hoff + 4];
    u16 hbv[8];
    for (int j = 0; j < 8; j++) {
      float rr = fsig(b2f(irp[j]) + b2f(hrp[j]));
      float zz = fsig(b2f(izp[j]) + b2f(hzp[j]));
      float nn = ftanh(b2f(inp[j]) + rr * b2f(hnp[j]));
      float ho = (1.f - zz) * nn + zz * hv[j];
      hv[j] = ho; hbv[j] = f2b(ho);
    }
    *(float4*)&teh_f[hoff] = *(const float4*)&hv[0];
    *(float4*)&teh_f[hoff + 4] = *(const float4*)&hv[4];
    *(uint4*)&teh_out[hoff] = *(const uint4*)&hbv[0];
    *(uint4*)&tehb[r][j8] = *(const uint4*)&hbv[0];
  }
  __syncthreads();

  // e2g: wave w computes n-tile w -> h directly in C-layout registers
  f32x4 hreg;
  {
    f32x4 acc = {};
#pragma unroll
    for (int ks = 0; ks < 16; ks++) {
      bf16x8 a = *(const bf16x8*)&tehb[mrow][ks * 32 + kq];
      bf16x8 b = *(const bf16x8*)&e2g_t[(size_t)(wave * 16 + mrow) * 512 + ks * 32 + kq];
      acc = __builtin_amdgcn_mfma_f32_16x16x32_bf16(a, b, acc, 0, 0, 0);
    }
    float bv = e2g_b[ncol];
#pragma unroll
    for (int r = 0; r < 4; r++) {
      float v = fmaxf(acc[r] + bv, 0.f);
      hreg[r] = v;
      ghb[0][rq4 + r][ncol] = f2b(v);
    }
  }
  __syncthreads();

  for (int t = 0; t < 12; t++) {
    int p = t & 1;
    // gates: read A-frags from gib + ghb[p]; 6 independent MFMA chains
    bf16x8 agi[4], agh[4];
#pragma unroll
    for (int ks = 0; ks < 4; ks++) {
      agi[ks] = *(const bf16x8*)&gib[mrow][ks * 32 + kq];
      agh[ks] = *(const bf16x8*)&ghb[p][mrow][ks * 32 + kq];
    }
    f32x4 gI[3], gH[3];
#pragma unroll
    for (int i = 0; i < 3; i++) {
      f32x4 a1 = {}, a2 = {};
#pragma unroll
      for (int ks = 0; ks < 4; ks++) {
        a1 = __builtin_amdgcn_mfma_f32_16x16x32_bf16(agi[ks], BfI[i][ks], a1, 0, 0, 0);
        a2 = __builtin_amdgcn_mfma_f32_16x16x32_bf16(agh[ks], BfH[i][ks], a2, 0, 0, 0);
      }
      gI[i] = a1; gH[i] = a2;
    }
    // register-only GRU pointwise; write new h into ghb[1-p] (no race with reads)
#pragma unroll
    for (int r = 0; r < 4; r++) {
      float rr = fsig(gI[0][r] + bI[0] + gH[0][r] + bH[0]);
      float zz = fsig(gI[1][r] + bI[1] + gH[1][r] + bH[1]);
      float nn = ftanh(gI[2][r] + bI[2] + rr * (gH[2][r] + bH[2]));
      float ho = (1.f - zz) * nn + zz * hreg[r];
      hreg[r] = ho;
      u16 hb = f2b(ho);
      ghb[1 - p][rq4 + r][ncol] = hb;
      goals[(size_t)(t * 512 + r0 + rq4 + r) * 128 + ncol] = hb;
    }
    __syncthreads();
    // phase 3: g2i -> gib tile w ; g2e -> gfe_l[t] tile w (reads ghb[1-p])
    bf16x8 ah[4];
#pragma unroll
    for (int ks = 0; ks < 4; ks++)
      ah[ks] = *(const bf16x8*)&ghb[1 - p][mrow][ks * 32 + kq];
    f32x4 ai = {}, ae = {};
#pragma unroll
    for (int ks = 0; ks < 4; ks++) {
      ai = __builtin_amdgcn_mfma_f32_16x16x32_bf16(ah[ks], GfI[ks], ai, 0, 0, 0);
      ae = __builtin_amdgcn_mfma_f32_16x16x32_bf16(ah[ks], GfE[ks], ae, 0, 0, 0);
    }
#pragma unroll
    for (int r = 0; r < 4; r++) {
      gib[rq4 + r][ncol] = f2b(fmaxf(ai[r] + bGi, 0.f));
      gfe_l[t][rq4 + r][ncol] = f2b(fmaxf(ae[r] + bGe, 0.f));
    }
    __syncthreads();
  }

  // encoder attention: 8 waves x 2 rows
#pragma unroll
  for (int rep = 0; rep < 2; rep++) {
    int m = wave + 8 * rep;
    float w0 = eaw[lane], w1 = eaw[lane + 64];
    float eb = eab[0];
    float v0[12], v1[12], lg[12];
#pragma unroll
    for (int t = 0; t < 12; t++) {
      float a = b2f(gfe_l[t][m][lane]);
      float c = b2f(gfe_l[t][m][lane + 64]);
      v0[t] = a; v1[t] = c;
      float pv = ftanh(a) * w0 + ftanh(c) * w1;
      for (int o = 32; o; o >>= 1) pv += __shfl_xor(pv, o);
      lg[t] = fmaxf(pv + eb, 0.f);
    }
    float mx = lg[0];
#pragma unroll
    for (int t = 1; t < 12; t++) mx = fmaxf(mx, lg[t]);
    float s = 0.f;
#pragma unroll
    for (int t = 0; t < 12; t++) { lg[t] = __expf(lg[t] - mx); s += lg[t]; }
    float inv = __fdividef(1.f, s);
    float c0 = 0.f, c1 = 0.f;
#pragma unroll
    for (int t = 0; t < 12; t++) { c0 += lg[t] * inv * v0[t]; c1 += lg[t] * inv * v1[t]; }
    gfe_out[(r0 + m) * 128 + lane] = f2b(c0);
    gfe_out[(r0 + m) * 128 + lane + 64] = f2b(c1);
  }
}

// ---------------------------------------------------------------- decoder ctx, suffix softmax
__global__ __launch_bounds__(256) void attn_ctx_all(const u16* __restrict__ gfd,  // [8,12,512,128]
                                                    const float* __restrict__ daw,
                                                    const float* __restrict__ dab,
                                                    u16* __restrict__ xctx) {      // [12,4096,128]
  int row = (blockIdx.x * 256 + threadIdx.x) >> 6;   // e*512 + b
  int lane = threadIdx.x & 63;
  int e = row >> 9, b = row & 511;
  float w0 = daw[lane], w1 = daw[lane + 64];
  float bias = dab[0];
  float v0[12], v1[12], lg[12];
#pragma unroll
  for (int s = 0; s < 12; s++) {
    size_t o = ((size_t)(e * 12 + s) * 512 + b) * 128;
    float a = b2f(gfd[o + lane]);
    float c = b2f(gfd[o + 64 + lane]);
    v0[s] = a; v1[s] = c;
    float p = ftanh(a) * w0 + ftanh(c) * w1;
    for (int o2 = 32; o2; o2 >>= 1) p += __shfl_xor(p, o2);
    lg[s] = fmaxf(p + bias, 0.f);
  }
  float base = fmaxf(bias, 0.f);
  float m = base;
#pragma unroll
  for (int s = 0; s < 12; s++) m = fmaxf(m, lg[s]);
  float eb = __expf(base - m);
  float el[12];
#pragma unroll
  for (int s = 0; s < 12; s++) el[s] = __expf(lg[s] - m);
  float S0 = 0.f, S1 = 0.f, sufE = 0.f;
#pragma unroll
  for (int td = 11; td >= 0; td--) {
    sufE += el[td];
    S0 += el[td] * v0[td];
    S1 += el[td] * v1[td];
    float inv = __fdividef(1.f, (float)td * eb + sufE);
    size_t o = ((size_t)td * 4096 + row) * 128;
    xctx[o + lane] = f2b(S0 * inv);
    xctx[o + lane + 64] = f2b(S1 * inv);
  }
}

// ================================================================ host
extern "C" void kernel_launch(void* const* d_in, const int* in_sizes, int n_in,
                              void* d_out, int out_size, void* d_ws, size_t ws_size,
                              hipStream_t stream) {
  const float* inp      = (const float*)d_in[0];
  const float* embed_w  = (const float*)d_in[1];
  const float* embed_b  = (const float*)d_in[2];
  const float* reg_w    = (const float*)d_in[3];
  const float* reg_b    = (const float*)d_in[4];
  const float* ea_w     = (const float*)d_in[5];
  const float* ea_b     = (const float*)d_in[6];
  const float* da_w     = (const float*)d_in[7];
  const float* da_b     = (const float*)d_in[8];
  const float* e2g_w    = (const float*)d_in[9];
  const float* e2g_b    = (const float*)d_in[10];
  const float* e2d_w    = (const float*)d_in[11];
  const float* e2d_b    = (const float*)d_in[12];
  const float* gh2i_w   = (const float*)d_in[13];
  const float* gh2i_b   = (const float*)d_in[14];
  const float* dh2i_w   = (const float*)d_in[15];
  const float* dh2i_b   = (const float*)d_in[16];
  const float* gh2t_w   = (const float*)d_in[17];
  const float* gh2t_b   = (const float*)d_in[18];
  const float* g2e_w    = (const float*)d_in[19];
  const float* g2e_b    = (const float*)d_in[20];
  const float* g2d_w    = (const float*)d_in[21];
  const float* g2d_b    = (const float*)d_in[22];
  const float* enc_wih  = (const float*)d_in[23];
  const float* enc_whh  = (const float*)d_in[24];
  const float* enc_bih  = (const float*)d_in[25];
  const float* enc_bhh  = (const float*)d_in[26];
  const float* goal_wih = (const float*)d_in[27];
  const float* goal_whh = (const float*)d_in[28];
  const float* goal_bih = (const float*)d_in[29];
  const float* goal_bhh = (const float*)d_in[30];
  const float* dec_wih  = (const float*)d_in[31];
  const float* dec_whh  = (const float*)d_in[32];
  const float* dec_bih  = (const float*)d_in[33];
  const float* dec_bhh  = (const float*)d_in[34];

  char* ws = (char*)d_ws;
  size_t off = 0;
  auto alloc = [&](size_t bytes) -> char* {
    char* p = ws + off; off += (bytes + 255) & ~(size_t)255; return p;
  };
  const size_t TSZ = 512 * 512;
  // ---- zero region (contiguous): teh_f, teh_hist, gfe_buf
  float* teh_f    = (float*)alloc(TSZ * 4);
  u16*   teh_hist = (u16*)  alloc(9 * TSZ * 2);
  u16*   gfe_buf  = (u16*)  alloc(512 * 128 * 2);
  size_t zero_bytes = off;
  u16*   traj     = (u16*)  alloc((size_t)8 * TSZ * 2);
  u16*   goals_all= (u16*)  alloc((size_t)8 * 6144 * 128 * 2); // [8][12,512,128]
  u16*   gfd      = (u16*)  alloc((size_t)49152 * 128 * 2);    // [8,12,512,128]
  u16*   xctx     = (u16*)  alloc((size_t)12 * 4096 * 128 * 2);
  float* dh_f     = (float*)alloc((size_t)4096 * 512 * 4);
  u16*   dh_b     = (u16*)  alloc((size_t)4096 * 512 * 2);
  u16*   ddi      = (u16*)  alloc((size_t)4096 * 512 * 2);
  u16*   giD      = (u16*)  alloc((size_t)4096 * 1536 * 2);
  u16*   ghD      = (u16*)  alloc((size_t)4096 * 1536 * 2);
  u16*   giE = giD, *ghE = ghD;                                // enc aliases rows 0:512
  u16* enc_wih_t  = (u16*)alloc((size_t)1536 * 640 * 2);
  u16* enc_whh_t  = (u16*)alloc((size_t)1536 * 512 * 2);
  u16* dec_wih_t  = (u16*)alloc((size_t)1536 * 640 * 2);
  u16* dec_whh_t  = (u16*)alloc((size_t)1536 * 512 * 2);
  u16* e2g_t      = (u16*)alloc(128 * 512 * 2);
  u16* e2d_t      = (u16*)alloc(512 * 512 * 2);
  u16* dh2i_t     = (u16*)alloc(512 * 512 * 2);
  u16* head_t     = (u16*)alloc(640 * 128 * 2);   // rows 0-511: gh2t_t, 512-639: g2d_t
  u16* g2e_t      = (u16*)alloc(128 * 128 * 2);
  u16* goal_wih_t = (u16*)alloc(384 * 128 * 2);
  u16* goal_whh_t = (u16*)alloc(384 * 128 * 2);
  u16* gh2i_t     = (u16*)alloc(128 * 128 * 2);
  if (off > ws_size) return;

  float* out_goal = (float*)d_out;
  float* out_dec  = out_goal + (size_t)512 * 8 * 12 * 2;

  hipMemsetAsync(teh_f, 0, zero_bytes, stream);

  // ---- all weight transposes in one dispatch
  TransArgs ta;
  int ntile = 0, ti = 0;
  auto push = [&](const float* in, u16* out, int K, int N) {
    ta.in[ti] = in; ta.out[ti] = out; ta.K[ti] = K; ta.N[ti] = N;
    ta.t0[ti] = ntile; ta.nx[ti] = N / 32;
    ntile += (K / 32) * (N / 32); ti++;
  };
  push(enc_wih, enc_wih_t, 640, 1536);
  push(enc_whh, enc_whh_t, 512, 1536);
  push(dec_wih, dec_wih_t, 640, 1536);
  push(dec_whh, dec_whh_t, 512, 1536);
  push(e2g_w, e2g_t, 512, 128);
  push(e2d_w, e2d_t, 512, 512);
  push(dh2i_w, dh2i_t, 512, 512);
  push(gh2t_w, head_t, 128, 512);
  push(g2d_w, head_t + 512 * 128, 128, 128);
  push(g2e_w, g2e_t, 128, 128);
  push(goal_wih, goal_wih_t, 128, 384);
  push(goal_whh, goal_whh_t, 128, 384);
  push(gh2i_w, gh2i_t, 128, 128);
  transpose_all<<<ntile, 256, 0, stream>>>(ta);

  embed_kernel<<<8192, 256, 0, stream>>>(inp, embed_w, embed_b, traj);

  const int FAR = 1 << 30;

  // ---------------- encoder chain (2 dispatches per step)
  for (int e = 0; e < 8; ++e) {
    GDesc dgi{traj + (size_t)e * TSZ, 512, gfe_buf, 128, 512,
              enc_wih_t, 640, enc_bih, giE, 1536, nullptr,
              nullptr, 0, FAR, 640, 0, 12, 4};
    GDesc dgh{teh_hist + (size_t)e * TSZ, 512, nullptr, 0, FAR,
              enc_whh_t, 512, enc_bhh, ghE, 1536, nullptr,
              nullptr, 0, FAR, 512, 0, 12, 4};
    gemm128<<<dim3(12, 4, 2), 256, 0, stream>>>(dgi, dgh);
    goal_mega<<<32, 512, 0, stream>>>(giE, ghE, teh_f, teh_hist + (size_t)(e + 1) * TSZ,
                                      e2g_t, e2g_b,
                                      goal_wih_t, goal_whh_t, goal_bih, goal_bhh,
                                      gh2i_t, gh2i_b, g2e_t, g2e_b, ea_w, ea_b,
                                      goals_all + (size_t)e * 6144 * 128, gfe_buf);
  }

  // ---------------- deferred batched encoder sinks
  {
    // fused goal head: out_goal directly from goals (no ghid, no atomics)
    head_reg<<<192, 256, 0, stream>>>(goals_all, head_t, gh2t_b, reg_w, reg_b, out_goal);
    // z=0: g2d -> gfd (M=49152, N=128, K=128); z=1: e2d -> dh (M=4096)
    GDesc dg2d{goals_all, 128, nullptr, 0, FAR,
               head_t + 512 * 128, 128, g2d_b, gfd, 128, nullptr,
               nullptr, 0, FAR, 128, 1, 1, 384};
    GDesc de2d{teh_hist + TSZ, 512, nullptr, 0, FAR,
               e2d_t, 512, e2d_b, dh_b, 512, dh_f,
               nullptr, 0, FAR, 512, 1, 4, 32};
    gemm128<<<dim3(4, 384, 2), 256, 0, stream>>>(dg2d, de2d);
    attn_ctx_all<<<1024, 256, 0, stream>>>(gfd, da_w, da_b, xctx);
    GDesc dd0{dh_b, 512, nullptr, 0, FAR,
              dh2i_t, 512, dh2i_b, ddi, 512, nullptr,
              nullptr, 0, FAR, 512, 1, 4, 32};
    gemm128<<<dim3(4, 32, 1), 256, 0, stream>>>(dd0, dd0);
  }

  // ---------------- batched decoder (2 dispatches per step)
  for (int td = 0; td < 12; ++td) {
    GDesc dgi{xctx + (size_t)td * 4096 * 128, 128, ddi, 512, 128,
              dec_wih_t, 640, dec_bih, giD, 1536, nullptr,
              nullptr, 0, FAR, 640, 0, 12, 32};
    GDesc dgh{dh_b, 512, nullptr, 0, FAR,
              dec_whh_t, 512, dec_bhh, ghD, 1536, nullptr,
              nullptr, 0, FAR, 512, 0, 12, 32};
    gemm128<<<dim3(12, 32, 2), 256, 0, stream>>>(dgi, dgh);
    gru_dh2i_reg<<<256, 1024, 0, stream>>>(giD, ghD, dh_f, dh_b, dh2i_t, dh2i_b, ddi,
                                           reg_w, reg_b, out_dec, td);
  }
}